// Round 13
// baseline (171.850 us; speedup 1.0000x reference)
//
#include <hip/hip_runtime.h>
#include <hip/hip_bf16.h>

#define SLEN 2048
#define HDIM 2048
#define NHEAD 32
#define KVHEAD 8
#define HEADD 64
#define NTOT 3104
#define NPAD 3200

typedef short bh8 __attribute__((ext_vector_type(8)));
typedef float f32x4 __attribute__((ext_vector_type(4)));

// 0.125 * log2(e): folded into Q so QK^T MFMA emits log2-domain scores
#define QSCALE 0.1803368801111204f

__device__ __forceinline__ unsigned short f2bf(float f) {
    union { float f; unsigned int u; } v; v.f = f;
    unsigned int u = v.u;
    return (unsigned short)((u + 0x7fffu + ((u >> 16) & 1u)) >> 16);
}

// HW packed f32->bf16 (RNE), 1 instruction instead of ~10 bit-ops
__device__ __forceinline__ unsigned int cvtpk_bf16(float lo, float hi) {
    unsigned int r;
    asm("v_cvt_pk_bf16_f32 %0, %1, %2" : "=v"(r) : "v"(lo), "v"(hi));
    return r;
}

__device__ __forceinline__ void gl_lds16(const unsigned short* g, unsigned short* l) {
    __builtin_amdgcn_global_load_lds(
        (const __attribute__((address_space(1))) unsigned int*)g,
        (__attribute__((address_space(3))) unsigned int*)l, 16, 0, 0);
}

// ---------------- RoPE cos/sin table: tab[s*32+d] = (cos, sin) of s*e^(-d*c) ----------------
__global__ void rope_tab_k(float* __restrict__ tab) {
    int i = blockIdx.x * 256 + threadIdx.x;   // 65536 entries
    int s = i >> 5, d = i & 31;
    float invf = __expf(-(float)d * (0.03125f * 13.815510557964274f));
    float ang = (float)s * invf;
    tab[(size_t)i * 2] = cosf(ang);
    tab[(size_t)i * 2 + 1] = sinf(ang);
}

// ---------------- cast hidden fp32 -> bf16 ----------------
__global__ void cast_x_k(const float* __restrict__ src, unsigned short* __restrict__ dst, int n) {
    int i = blockIdx.x * blockDim.x + threadIdx.x;
    int base = i * 4;
    if (base < n) {
        float4 f = *(const float4*)(src + base);
        ushort4 o;
        o.x = f2bf(f.x); o.y = f2bf(f.y); o.z = f2bf(f.z); o.w = f2bf(f.w);
        *(ushort4*)(dst + base) = o;
    }
}

// ---------------- pack [Q | K | V | gates] transposed -> bf16 (NPAD x HDIM) ----------------
__global__ void pack_wt_k(const float* __restrict__ Wq, const float* __restrict__ Wk,
                          const float* __restrict__ Wv, unsigned short* __restrict__ Wt) {
    __shared__ float tile[32][33];
    int n0 = blockIdx.x * 32, k0 = blockIdx.y * 32;
    int t = threadIdx.x;
    for (int i = 0; i < 4; i++) {
        int idx = i * 256 + t;
        int kr = idx >> 5, nc = idx & 31;
        int n = n0 + nc, k = k0 + kr;
        float val = 0.f;
        if (n < 2048)       { int h = n >> 6, d = n & 63; val = Wq[(size_t)k * 2080 + (h >> 2) * 260 + (h & 3) * 64 + d]; }
        else if (n < 2560)  { val = Wk[(size_t)k * 512 + (n - 2048)]; }
        else if (n < 3072)  { val = Wv[(size_t)k * 512 + (n - 2560)]; }
        else if (n < 3104)  { int h = n - 3072;           val = Wq[(size_t)k * 2080 + (h >> 2) * 260 + 256 + (h & 3)]; }
        tile[kr][nc] = val;
    }
    __syncthreads();
    for (int i = 0; i < 4; i++) {
        int idx = i * 256 + t;
        int nr = idx >> 5, kc = idx & 31;
        Wt[(size_t)(n0 + nr) * HDIM + (k0 + kc)] = f2bf(tile[kc][nr]);
    }
}

// ---------------- transpose-cast Wo -> bf16 (2048 x 2048) ----------------
__global__ void pack_wot_k(const float* __restrict__ Wo, unsigned short* __restrict__ Wt) {
    __shared__ float tile[32][33];
    int n0 = blockIdx.x * 32, k0 = blockIdx.y * 32;
    int t = threadIdx.x;
    for (int i = 0; i < 4; i++) {
        int idx = i * 256 + t;
        int kr = idx >> 5, nc = idx & 31;
        tile[kr][nc] = Wo[(size_t)(k0 + kr) * 2048 + (n0 + nc)];
    }
    __syncthreads();
    for (int i = 0; i < 4; i++) {
        int idx = i * 256 + t;
        int nr = idx >> 5, kc = idx & 31;
        Wt[(size_t)(n0 + nr) * 2048 + (k0 + kc)] = f2bf(tile[kc][nr]);
    }
}

// ---------------- NT GEMM, 64x128 tile, templated (R12 structure, unchanged) ----------------
template<int NST, bool FUSE>
__global__ __launch_bounds__(256) void gemm_nt64_k(const unsigned short* __restrict__ A,
                                                   const unsigned short* __restrict__ Bt,
                                                   float* __restrict__ C0,
                                                   float* __restrict__ C1,
                                                   int ldc, int mtiles, int ntiles,
                                                   unsigned short* __restrict__ Qr,
                                                   unsigned short* __restrict__ Kr,
                                                   float* __restrict__ gate,
                                                   const float* __restrict__ g_q,
                                                   const float* __restrict__ g_k,
                                                   const float* __restrict__ tab) {
    const int K = 2048;
    __shared__ unsigned short As[3][64 * 32];
    __shared__ unsigned short Bs[3][128 * 32];
    int d = blockIdx.x;
    int nwg = gridDim.x;
    int cpx = nwg >> 3;
    int swz = (d & 7) * cpx + (d >> 3);
    int half = (swz >= ntiles) ? 1 : 0;
    int tile = swz - half * ntiles;
    int m0 = (tile % mtiles) * 64, n0 = (tile / mtiles) * 128;
    float* C = half ? C1 : C0;
    int koff = half * (NST * 32);
    int t = threadIdx.x;
    int w = t >> 6, l = t & 63;
    int wm = (w >> 1) * 32, wn = (w & 1) * 64;
    int lrow = l & 15, lc = l >> 4;
    int rsw = (lrow >> 1) & 3;
    int scol = ((l & 3) ^ ((l >> 3) & 3)) * 8;

    f32x4 acc[2][4];
    #pragma unroll
    for (int i = 0; i < 2; i++)
        #pragma unroll
        for (int j = 0; j < 4; j++)
            acc[i][j] = {0.f, 0.f, 0.f, 0.f};

    const unsigned short* ga = &A[(size_t)(m0 + w * 16 + (l >> 2)) * K + koff + scol];
    const unsigned short* gb = &Bt[(size_t)(n0 + w * 32 + (l >> 2)) * K + koff + scol];

#define STAGE_NT64(s, b) do { \
        gl_lds16(ga + (size_t)(s) * 32,                  &As[b][w * 512]); \
        gl_lds16(gb + (size_t)(s) * 32,                  &Bs[b][(w * 2 + 0) * 512]); \
        gl_lds16(gb + (size_t)(s) * 32 + 16 * (size_t)K, &Bs[b][(w * 2 + 1) * 512]); \
    } while (0)

#define GBODY(rb) do { \
        bh8 af[2], bb[4]; \
        _Pragma("unroll") \
        for (int i = 0; i < 2; i++) \
            af[i] = *(const bh8*)(&As[rb][(wm + i * 16 + lrow) * 32 + ((lc ^ rsw) * 8)]); \
        _Pragma("unroll") \
        for (int j = 0; j < 4; j++) \
            bb[j] = *(const bh8*)(&Bs[rb][(wn + j * 16 + lrow) * 32 + ((lc ^ rsw) * 8)]); \
        _Pragma("unroll") \
        for (int i = 0; i < 2; i++) \
            _Pragma("unroll") \
            for (int j = 0; j < 4; j++) \
                acc[i][j] = __builtin_amdgcn_mfma_f32_16x16x32_bf16(af[i], bb[j], acc[i][j], 0, 0, 0); \
    } while (0)

#define WB3 asm volatile("s_waitcnt vmcnt(3)\n\ts_barrier" ::: "memory")

    STAGE_NT64(0, 0);
    STAGE_NT64(1, 1);
    if constexpr (NST == 64) {
        for (int sb = 0; sb < 60; sb += 3) {
            WB3;
            STAGE_NT64(sb + 2, 2);
            GBODY(0);
            WB3;
            STAGE_NT64(sb + 3, 0);
            GBODY(1);
            WB3;
            STAGE_NT64(sb + 4, 1);
            GBODY(2);
        }
        WB3;
        STAGE_NT64(62, 2);
        GBODY(0);
        WB3;
        STAGE_NT64(63, 0);
        GBODY(1);
        WB3;
        GBODY(2);
        asm volatile("s_waitcnt vmcnt(0)\n\ts_barrier" ::: "memory");
        GBODY(0);
    } else {
        for (int sb = 0; sb < 30; sb += 3) {
            WB3;
            STAGE_NT64(sb + 2, 2);
            GBODY(0);
            WB3;
            STAGE_NT64(sb + 3, 0);
            GBODY(1);
            WB3;
            STAGE_NT64(sb + 4, 1);
            GBODY(2);
        }
        WB3;
        GBODY(0);
        asm volatile("s_waitcnt vmcnt(0)\n\ts_barrier" ::: "memory");
        GBODY(1);
    }
#undef WB3
#undef STAGE_NT64
#undef GBODY
    int col = l & 15, rbase = (l >> 4) * 4;
    if constexpr (FUSE) {
        int nt = n0 >> 7;
        if (nt < 20) {
            bool isQ = nt < 16;
            int hd = ((n0 + wn) - (isQ ? 0 : 2048)) >> 6;
            unsigned short* dst = (isQ ? Qr : Kr) + (size_t)hd * SLEN * 64;
            const float* gv = isQ ? g_q : g_k;
            float g0 = gv[col], g1 = gv[col + 16], g2 = gv[col + 32], g3 = gv[col + 48];
            float qs = isQ ? QSCALE : 1.0f;
            #pragma unroll
            for (int i = 0; i < 2; i++)
                #pragma unroll
                for (int r = 0; r < 4; r++) {
                    int s = m0 + wm + i * 16 + rbase + r;
                    float x0 = acc[i][0][r], x1 = acc[i][1][r];
                    float x2 = acc[i][2][r], x3 = acc[i][3][r];
                    float sq = x0 * x0 + x1 * x1 + x2 * x2 + x3 * x3;
                    sq += __shfl_xor(sq, 1);
                    sq += __shfl_xor(sq, 2);
                    sq += __shfl_xor(sq, 4);
                    sq += __shfl_xor(sq, 8);
                    float inv = rsqrtf(sq * (1.f / 64.f) + 1e-6f);
                    float xn0 = x0 * inv * g0, xn1 = x1 * inv * g1;
                    float xn2 = x2 * inv * g2, xn3 = x3 * inv * g3;
                    const float* te = tab + (size_t)s * 64;
                    float2 cs0 = *(const float2*)(te + col * 2);
                    float2 cs1 = *(const float2*)(te + (col + 16) * 2);
                    unsigned short* dr = dst + (size_t)s * 64;
                    dr[col]      = f2bf((xn0 * cs0.x - xn2 * cs0.y) * qs);
                    dr[col + 16] = f2bf((xn1 * cs1.x - xn3 * cs1.y) * qs);
                    dr[col + 32] = f2bf((xn2 * cs0.x + xn0 * cs0.y) * qs);
                    dr[col + 48] = f2bf((xn3 * cs1.x + xn1 * cs1.y) * qs);
                }
        } else if (nt < 24) {
            for (int i = 0; i < 2; i++)
                for (int j = 0; j < 4; j++)
                    #pragma unroll
                    for (int r = 0; r < 4; r++)
                        C[(size_t)(m0 + wm + i * 16 + rbase + r) * ldc + (n0 + wn + j * 16 + col)] = acc[i][j][r];
        } else {
            if (wn == 0) {
                #pragma unroll
                for (int i = 0; i < 2; i++)
                    #pragma unroll
                    for (int j = 0; j < 2; j++)
                        #pragma unroll
                        for (int r = 0; r < 4; r++) {
                            int s = m0 + wm + i * 16 + rbase + r;
                            int h = j * 16 + col;
                            gate[s * 32 + h] = 1.f / (1.f + __expf(-acc[i][j][r]));
                        }
            }
        }
    } else {
        for (int i = 0; i < 2; i++)
            for (int j = 0; j < 4; j++)
                #pragma unroll
                for (int r = 0; r < 4; r++)
                    C[(size_t)(m0 + wm + i * 16 + rbase + r) * ldc + (n0 + wn + j * 16 + col)] = acc[i][j][r];
    }
}

// ---------------- out-proj split-K reduce: out = P0 + P1 (2048^2 f32) ----------------
__global__ void addf4_k(const float* __restrict__ a, const float* __restrict__ b,
                        float* __restrict__ o) {
    int i = (blockIdx.x * 256 + threadIdx.x) * 4;
    float4 x = *(const float4*)(a + i);
    float4 y = *(const float4*)(b + i);
    float4 r; r.x = x.x + y.x; r.y = x.y + y.y; r.z = x.z + y.z; r.w = x.w + y.w;
    *(float4*)(o + i) = r;
}

// ---------------- V transpose + key-permute: QKVG[s][2560+hh*64+d] -> Vt[hh][d][perm(s)] ----
__global__ void vt_k(const float* __restrict__ QKVG, unsigned short* __restrict__ Vt) {
    __shared__ float tile[64][65];
    int s0 = blockIdx.x * 64, hh = blockIdx.y;
    int t = threadIdx.x;
    #pragma unroll
    for (int i = 0; i < 4; i++) {
        int idx = i * 256 + t;
        int sr = idx >> 4, c4 = (idx & 15) * 4;
        float4 f = *(const float4*)(&QKVG[(size_t)(s0 + sr) * NPAD + 2560 + hh * 64 + c4]);
        tile[sr][c4] = f.x; tile[sr][c4 + 1] = f.y; tile[sr][c4 + 2] = f.z; tile[sr][c4 + 3] = f.w;
    }
    __syncthreads();
    #pragma unroll
    for (int i = 0; i < 4; i++) {
        int idx = i * 256 + t;
        int dr = idx >> 4, c4 = (idx & 15) * 4;
        int hb = c4 >> 5, f = (c4 >> 4) & 1, g = (c4 >> 2) & 3;
        int p = (hb * 4 + g) * 8 + f * 4;
        ushort4 o;
        o.x = f2bf(tile[c4][dr]); o.y = f2bf(tile[c4 + 1][dr]);
        o.z = f2bf(tile[c4 + 2][dr]); o.w = f2bf(tile[c4 + 3][dr]);
        *(ushort4*)(&Vt[((size_t)hh * 64 + dr) * SLEN + s0 + p]) = o;
    }
}

// ---------------- causal GQA flash attention + gate ----------------
// R13: two adjacent q-strips per wave (qta=2u, qtb=2u+1), 512 blocks big-first.
// Per K/V tile each kb/vb fragment is read from LDS ONCE and feeds MFMAs for BOTH
// strips -- halves LDS read traffic (was 4 waves x identical reads) and halves K/V
// staging. Main loop is branch-free (both strips); one peeled B-only final tile.
__global__ __launch_bounds__(256) void attn_k(const unsigned short* __restrict__ Qr,
                                              const unsigned short* __restrict__ Kr,
                                              const unsigned short* __restrict__ Vt,
                                              const float* __restrict__ gate,
                                              unsigned short* __restrict__ attn) {
    __shared__ unsigned short Kls[3][64 * 64];
    __shared__ unsigned short Vls[3][64 * 64];
    int d = blockIdx.x;                 // 512
    int kvh = d & 7;
    int h = kvh * 4 + ((d >> 3) & 3);
    int u = 15 - (d >> 5);              // big-first pair index
    int qta = 2 * u, qtb = 2 * u + 1;
    int T = qtb + 1;                    // tiles to stream (>= 2 always)
    int t = threadIdx.x, w = t >> 6, l = t & 63;
    int ql = l & 15, g = l >> 4;
    const float NEGINF = -__builtin_inff();

    const unsigned short* Kh = Kr + (size_t)kvh * SLEN * 64;
    const unsigned short* Vh = Vt + (size_t)kvh * 64 * SLEN;
    const unsigned short* Qh = Qr + (size_t)h * SLEN * 64;
    int lk = g * 8;
    int r8 = l >> 3, c8 = l & 7;
    int cs = 8 * (c8 ^ r8);
    int R0 = w * 16, R1 = w * 16 + 8;
    int rdswz = (ql & 7) << 4;

    int q0a = qta * 64, q0b = qtb * 64;
    int qrowa = q0a + w * 16 + ql;
    int qrowb = q0b + w * 16 + ql;

    bh8 qaA0 = *(const bh8*)(Qh + (size_t)qrowa * 64 + lk);
    bh8 qaA1 = *(const bh8*)(Qh + (size_t)qrowa * 64 + 32 + lk);
    bh8 qaB0 = *(const bh8*)(Qh + (size_t)qrowb * 64 + lk);
    bh8 qaB1 = *(const bh8*)(Qh + (size_t)qrowb * 64 + 32 + lk);

    f32x4 oA[4], oB[4];
    #pragma unroll
    for (int i = 0; i < 4; i++) { oA[i] = {0.f, 0.f, 0.f, 0.f}; oB[i] = {0.f, 0.f, 0.f, 0.f}; }
    float m2a = NEGINF, lsa = 0.f;
    float m2b = NEGINF, lsb = 0.f;

    // prologue: stage tiles 0,1 (T >= 2 always)
    gl_lds16(&Kh[(size_t)(0 + R0 + r8) * 64 + cs], &Kls[0][R0 * 64]);
    gl_lds16(&Kh[(size_t)(0 + R1 + r8) * 64 + cs], &Kls[0][R1 * 64]);
    gl_lds16(&Vh[(size_t)(R0 + r8) * SLEN + 0 + cs], &Vls[0][R0 * 64]);
    gl_lds16(&Vh[(size_t)(R1 + r8) * SLEN + 0 + cs], &Vls[0][R1 * 64]);
    gl_lds16(&Kh[(size_t)(64 + R0 + r8) * 64 + cs], &Kls[1][R0 * 64]);
    gl_lds16(&Kh[(size_t)(64 + R1 + r8) * 64 + cs], &Kls[1][R1 * 64]);
    gl_lds16(&Vh[(size_t)(R0 + r8) * SLEN + 64 + cs], &Vls[1][R0 * 64]);
    gl_lds16(&Vh[(size_t)(R1 + r8) * SLEN + 64 + cs], &Vls[1][R1 * 64]);
    int rd = 0, wr = 2;

    // ---- main loop: tiles 0..T-2, BOTH strips active (ti <= qta)
    for (int ti = 0; ti < T - 1; ti++) {
        asm volatile("s_waitcnt vmcnt(4)\n\ts_barrier" ::: "memory");
        if (ti + 2 < T) {
            int kv1 = (ti + 2) * 64;
            gl_lds16(&Kh[(size_t)(kv1 + R0 + r8) * 64 + cs], &Kls[wr][R0 * 64]);
            gl_lds16(&Kh[(size_t)(kv1 + R1 + r8) * 64 + cs], &Kls[wr][R1 * 64]);
            gl_lds16(&Vh[(size_t)(R0 + r8) * SLEN + kv1 + cs], &Vls[wr][R0 * 64]);
            gl_lds16(&Vh[(size_t)(R1 + r8) * SLEN + kv1 + cs], &Vls[wr][R1 * 64]);
        }
        const unsigned short* Kb = &Kls[rd][0];
        const unsigned short* Vb = &Vls[rd][0];
        int kv0 = ti * 64;
        // ---- QK^T both strips (kb read once)
        f32x4 sa[4], sb[4];
        __builtin_amdgcn_s_setprio(1);
        #pragma unroll
        for (int nt = 0; nt < 4; nt++) {
            int rb = (nt * 16 + ql) * 128;
            bh8 kb0 = *(const bh8*)(&Kb[(rb + ((g * 16) ^ rdswz)) >> 1]);
            bh8 kb1 = *(const bh8*)(&Kb[(rb + ((64 + g * 16) ^ rdswz)) >> 1]);
            f32x4 a = {0.f, 0.f, 0.f, 0.f};
            a = __builtin_amdgcn_mfma_f32_16x16x32_bf16(kb0, qaA0, a, 0, 0, 0);
            a = __builtin_amdgcn_mfma_f32_16x16x32_bf16(kb1, qaA1, a, 0, 0, 0);
            sa[nt] = a;
            f32x4 b = {0.f, 0.f, 0.f, 0.f};
            b = __builtin_amdgcn_mfma_f32_16x16x32_bf16(kb0, qaB0, b, 0, 0, 0);
            b = __builtin_amdgcn_mfma_f32_16x16x32_bf16(kb1, qaB1, b, 0, 0, 0);
            sb[nt] = b;
        }
        __builtin_amdgcn_s_setprio(0);
        // ---- causal mask for strip A at its diag tile (B's diag is the peeled tile)
        if (ti == qta) {
            #pragma unroll
            for (int nt = 0; nt < 4; nt++)
                #pragma unroll
                for (int j = 0; j < 4; j++) {
                    int key = kv0 + nt * 16 + 4 * g + j;
                    if (key > qrowa) sa[nt][j] = NEGINF;
                }
        }
        // ---- softmax strip A
        {
            float mt0 = fmaxf(fmaxf(sa[0][0], sa[0][1]), fmaxf(sa[0][2], sa[0][3]));
            float mt1 = fmaxf(fmaxf(sa[1][0], sa[1][1]), fmaxf(sa[1][2], sa[1][3]));
            float mt2 = fmaxf(fmaxf(sa[2][0], sa[2][1]), fmaxf(sa[2][2], sa[2][3]));
            float mt3 = fmaxf(fmaxf(sa[3][0], sa[3][1]), fmaxf(sa[3][2], sa[3][3]));
            float mt = fmaxf(fmaxf(mt0, mt1), fmaxf(mt2, mt3));
            mt = fmaxf(mt, __shfl_xor(mt, 16));
            mt = fmaxf(mt, __shfl_xor(mt, 32));
            if (!__all(mt - m2a <= 8.f)) {
                float mnew = fmaxf(m2a, mt);
                float resc = __builtin_amdgcn_exp2f(m2a - mnew);
                m2a = mnew;
                lsa *= resc;
                float rf[4];
                #pragma unroll
                for (int j = 0; j < 4; j++) rf[j] = __shfl(resc, 4 * g + j);
                #pragma unroll
                for (int nt = 0; nt < 4; nt++) {
                    f32x4 oo = oA[nt];
                    #pragma unroll
                    for (int j = 0; j < 4; j++) oo[j] *= rf[j];
                    oA[nt] = oo;
                }
            }
            float ps = 0.f;
            #pragma unroll
            for (int nt = 0; nt < 4; nt++)
                #pragma unroll
                for (int j = 0; j < 4; j++) {
                    float p = __builtin_amdgcn_exp2f(sa[nt][j] - m2a);
                    sa[nt][j] = p;
                    ps += p;
                }
            ps += __shfl_xor(ps, 16);
            ps += __shfl_xor(ps, 32);
            lsa += ps;
        }
        // ---- softmax strip B (never masked in main loop: ti <= qta < qtb)
        {
            float mt0 = fmaxf(fmaxf(sb[0][0], sb[0][1]), fmaxf(sb[0][2], sb[0][3]));
            float mt1 = fmaxf(fmaxf(sb[1][0], sb[1][1]), fmaxf(sb[1][2], sb[1][3]));
            float mt2 = fmaxf(fmaxf(sb[2][0], sb[2][1]), fmaxf(sb[2][2], sb[2][3]));
            float mt3 = fmaxf(fmaxf(sb[3][0], sb[3][1]), fmaxf(sb[3][2], sb[3][3]));
            float mt = fmaxf(fmaxf(mt0, mt1), fmaxf(mt2, mt3));
            mt = fmaxf(mt, __shfl_xor(mt, 16));
            mt = fmaxf(mt, __shfl_xor(mt, 32));
            if (!__all(mt - m2b <= 8.f)) {
                float mnew = fmaxf(m2b, mt);
                float resc = __builtin_amdgcn_exp2f(m2b - mnew);
                m2b = mnew;
                lsb *= resc;
                float rf[4];
                #pragma unroll
                for (int j = 0; j < 4; j++) rf[j] = __shfl(resc, 4 * g + j);
                #pragma unroll
                for (int nt = 0; nt < 4; nt++) {
                    f32x4 oo = oB[nt];
                    #pragma unroll
                    for (int j = 0; j < 4; j++) oo[j] *= rf[j];
                    oB[nt] = oo;
                }
            }
            float ps = 0.f;
            #pragma unroll
            for (int nt = 0; nt < 4; nt++)
                #pragma unroll
                for (int j = 0; j < 4; j++) {
                    float p = __builtin_amdgcn_exp2f(sb[nt][j] - m2b);
                    sb[nt][j] = p;
                    ps += p;
                }
            ps += __shfl_xor(ps, 16);
            ps += __shfl_xor(ps, 32);
            lsb += ps;
        }
        // ---- pack P both strips
        union { unsigned int uu[4]; bh8 v; } pa0, pa1, pb0, pb1;
        pa0.uu[0] = cvtpk_bf16(sa[0][0], sa[0][1]); pa0.uu[1] = cvtpk_bf16(sa[0][2], sa[0][3]);
        pa0.uu[2] = cvtpk_bf16(sa[1][0], sa[1][1]); pa0.uu[3] = cvtpk_bf16(sa[1][2], sa[1][3]);
        pa1.uu[0] = cvtpk_bf16(sa[2][0], sa[2][1]); pa1.uu[1] = cvtpk_bf16(sa[2][2], sa[2][3]);
        pa1.uu[2] = cvtpk_bf16(sa[3][0], sa[3][1]); pa1.uu[3] = cvtpk_bf16(sa[3][2], sa[3][3]);
        pb0.uu[0] = cvtpk_bf16(sb[0][0], sb[0][1]); pb0.uu[1] = cvtpk_bf16(sb[0][2], sb[0][3]);
        pb0.uu[2] = cvtpk_bf16(sb[1][0], sb[1][1]); pb0.uu[3] = cvtpk_bf16(sb[1][2], sb[1][3]);
        pb1.uu[0] = cvtpk_bf16(sb[2][0], sb[2][1]); pb1.uu[1] = cvtpk_bf16(sb[2][2], sb[2][3]);
        pb1.uu[2] = cvtpk_bf16(sb[3][0], sb[3][1]); pb1.uu[3] = cvtpk_bf16(sb[3][2], sb[3][3]);
        // ---- PV both strips (vb read once)
        __builtin_amdgcn_s_setprio(1);
        #pragma unroll
        for (int nt = 0; nt < 4; nt++) {
            int rb = (nt * 16 + ql) * 128;
            bh8 vb0 = *(const bh8*)(&Vb[(rb + ((g * 16) ^ rdswz)) >> 1]);
            bh8 vb1 = *(const bh8*)(&Vb[(rb + ((64 + g * 16) ^ rdswz)) >> 1]);
            oA[nt] = __builtin_amdgcn_mfma_f32_16x16x32_bf16(pa0.v, vb0, oA[nt], 0, 0, 0);
            oA[nt] = __builtin_amdgcn_mfma_f32_16x16x32_bf16(pa1.v, vb1, oA[nt], 0, 0, 0);
            oB[nt] = __builtin_amdgcn_mfma_f32_16x16x32_bf16(pb0.v, vb0, oB[nt], 0, 0, 0);
            oB[nt] = __builtin_amdgcn_mfma_f32_16x16x32_bf16(pb1.v, vb1, oB[nt], 0, 0, 0);
        }
        __builtin_amdgcn_s_setprio(0);
        rd = (rd == 2) ? 0 : rd + 1;
        wr = (wr == 2) ? 0 : wr + 1;
    }

    // ---- peeled final tile (ti = qtb): strip B only, with B's causal mask
    {
        asm volatile("s_waitcnt vmcnt(0)\n\ts_barrier" ::: "memory");
        const unsigned short* Kb = &Kls[rd][0];
        const unsigned short* Vb = &Vls[rd][0];
        int kv0 = qtb * 64;
        f32x4 sb[4];
        __builtin_amdgcn_s_setprio(1);
        #pragma unroll
        for (int nt = 0; nt < 4; nt++) {
            int rb = (nt * 16 + ql) * 128;
            bh8 kb0 = *(const bh8*)(&Kb[(rb + ((g * 16) ^ rdswz)) >> 1]);
            bh8 kb1 = *(const bh8*)(&Kb[(rb + ((64 + g * 16) ^ rdswz)) >> 1]);
            f32x4 b = {0.f, 0.f, 0.f, 0.f};
            b = __builtin_amdgcn_mfma_f32_16x16x32_bf16(kb0, qaB0, b, 0, 0, 0);
            b = __builtin_amdgcn_mfma_f32_16x16x32_bf16(kb1, qaB1, b, 0, 0, 0);
            sb[nt] = b;
        }
        __builtin_amdgcn_s_setprio(0);
        #pragma unroll
        for (int nt = 0; nt < 4; nt++)
            #pragma unroll
            for (int j = 0; j < 4; j++) {
                int key = kv0 + nt * 16 + 4 * g + j;
                if (key > qrowb) sb[nt][j] = NEGINF;
            }
        float mt0 = fmaxf(fmaxf(sb[0][0], sb[0][1]), fmaxf(sb[0][2], sb[0][3]));
        float mt1 = fmaxf(fmaxf(sb[1][0], sb[1][1]), fmaxf(sb[1][2], sb[1][3]));
        float mt2 = fmaxf(fmaxf(sb[2][0], sb[2][1]), fmaxf(sb[2][2], sb[2][3]));
        float mt3 = fmaxf(fmaxf(sb[3][0], sb[3][1]), fmaxf(sb[3][2], sb[3][3]));
        float mt = fmaxf(fmaxf(mt0, mt1), fmaxf(mt2, mt3));
        mt = fmaxf(mt, __shfl_xor(mt, 16));
        mt = fmaxf(mt, __shfl_xor(mt, 32));
        if (!__all(mt - m2b <= 8.f)) {
            float mnew = fmaxf(m2b, mt);
            float resc = __builtin_amdgcn_exp2f(m2b - mnew);
            m2b = mnew;
            lsb *= resc;
            float rf[4];
            #pragma unroll
            for (int j = 0; j < 4; j++) rf[j] = __shfl(resc, 4 * g + j);
            #pragma unroll
            for (int nt = 0; nt < 4; nt++) {
                f32x4 oo = oB[nt];
                #pragma unroll
                for (int j = 0; j < 4; j++) oo[j] *= rf[j];
                oB[nt] = oo;
            }
        }
        float ps = 0.f;
        #pragma unroll
        for (int nt = 0; nt < 4; nt++)
            #pragma unroll
            for (int j = 0; j < 4; j++) {
                float p = __builtin_amdgcn_exp2f(sb[nt][j] - m2b);
                sb[nt][j] = p;
                ps += p;
            }
        ps += __shfl_xor(ps, 16);
        ps += __shfl_xor(ps, 32);
        lsb += ps;
        union { unsigned int uu[4]; bh8 v; } pb0, pb1;
        pb0.uu[0] = cvtpk_bf16(sb[0][0], sb[0][1]); pb0.uu[1] = cvtpk_bf16(sb[0][2], sb[0][3]);
        pb0.uu[2] = cvtpk_bf16(sb[1][0], sb[1][1]); pb0.uu[3] = cvtpk_bf16(sb[1][2], sb[1][3]);
        pb1.uu[0] = cvtpk_bf16(sb[2][0], sb[2][1]); pb1.uu[1] = cvtpk_bf16(sb[2][2], sb[2][3]);
        pb1.uu[2] = cvtpk_bf16(sb[3][0], sb[3][1]); pb1.uu[3] = cvtpk_bf16(sb[3][2], sb[3][3]);
        __builtin_amdgcn_s_setprio(1);
        #pragma unroll
        for (int nt = 0; nt < 4; nt++) {
            int rb = (nt * 16 + ql) * 128;
            bh8 vb0 = *(const bh8*)(&Vb[(rb + ((g * 16) ^ rdswz)) >> 1]);
            bh8 vb1 = *(const bh8*)(&Vb[(rb + ((64 + g * 16) ^ rdswz)) >> 1]);
            oB[nt] = __builtin_amdgcn_mfma_f32_16x16x32_bf16(pb0.v, vb0, oB[nt], 0, 0, 0);
            oB[nt] = __builtin_amdgcn_mfma_f32_16x16x32_bf16(pb1.v, vb1, oB[nt], 0, 0, 0);
        }
        __builtin_amdgcn_s_setprio(0);
    }

    // ---- epilogue: both strips
    {
        float gf[4];
        #pragma unroll
        for (int j = 0; j < 4; j++) {
            float ls = __shfl(lsa, 4 * g + j);
            int row = q0a + w * 16 + 4 * g + j;
            gf[j] = gate[row * 32 + h] / ls;
        }
        #pragma unroll
        for (int j = 0; j < 4; j++) {
            int row = q0a + w * 16 + 4 * g + j;
            #pragma unroll
            for (int nt = 0; nt < 4; nt++)
                attn[(size_t)row * 2048 + h * 64 + nt * 16 + ql] = f2bf(oA[nt][j] * gf[j]);
        }
    }
    {
        float gf[4];
        #pragma unroll
        for (int j = 0; j < 4; j++) {
            float ls = __shfl(lsb, 4 * g + j);
            int row = q0b + w * 16 + 4 * g + j;
            gf[j] = gate[row * 32 + h] / ls;
        }
        #pragma unroll
        for (int j = 0; j < 4; j++) {
            int row = q0b + w * 16 + 4 * g + j;
            #pragma unroll
            for (int nt = 0; nt < 4; nt++)
                attn[(size_t)row * 2048 + h * 64 + nt * 16 + ql] = f2bf(oB[nt][j] * gf[j]);
        }
    }
}

extern "C" void kernel_launch(void* const* d_in, const int* in_sizes, int n_in,
                              void* d_out, int out_size, void* d_ws, size_t ws_size,
                              hipStream_t stream) {
    const float* hidden = (const float*)d_in[0];
    const float* Wq = (const float*)d_in[1];
    const float* Wk = (const float*)d_in[2];
    const float* Wv = (const float*)d_in[3];
    const float* Wo = (const float*)d_in[4];
    const float* gq = (const float*)d_in[5];
    const float* gk = (const float*)d_in[6];
    float* out = (float*)d_out;
    char* ws = (char*)d_ws;

    unsigned short* X     = (unsigned short*)(ws + 0);         //  8388608 B
    unsigned short* Wt    = (unsigned short*)(ws + 8388608);   // 13107200 B
    float*          QKVG  = (float*)(ws + 21495808);           // 26214400 B (V cols only; reused as P0)
    unsigned short* Qr    = (unsigned short*)(ws + 47710208);  //  8388608 B
    unsigned short* Kr    = (unsigned short*)(ws + 56098816);  //  2097152 B
    unsigned short* Vt    = (unsigned short*)(ws + 58195968);  //  2097152 B
    float*          gate  = (float*)(ws + 60293120);           //   262144 B
    unsigned short* attnb = (unsigned short*)(ws + 60555264);  //  8388608 B
    unsigned short* Wot   = (unsigned short*)(ws + 68943872);  //  8388608 B
    float*          P1    = (float*)(ws + 77332480);           // 16777216 B (out-proj split-K partial)
    float*          rtab  = (float*)(ws + 94109696);           //   524288 B (RoPE cos/sin table)
    float*          P0    = QKVG;                              // dead after vt_k

    rope_tab_k<<<dim3(256), dim3(256), 0, stream>>>(rtab);
    cast_x_k<<<dim3(4096), dim3(256), 0, stream>>>(hidden, X, SLEN * HDIM);
    pack_wt_k<<<dim3(100, 64), dim3(256), 0, stream>>>(Wq, Wk, Wv, Wt);
    pack_wot_k<<<dim3(64, 64), dim3(256), 0, stream>>>(Wo, Wot);
    gemm_nt64_k<64, true><<<dim3(800), dim3(256), 0, stream>>>(X, Wt, QKVG, QKVG, NPAD, 32, 800,
                                                               Qr, Kr, gate, gq, gk, rtab);
    vt_k<<<dim3(32, 8), dim3(256), 0, stream>>>(QKVG, Vt);
    attn_k<<<dim3(512), dim3(256), 0, stream>>>(Qr, Kr, Vt, gate, attnb);
    gemm_nt64_k<32, false><<<dim3(1024), dim3(256), 0, stream>>>(attnb, Wot, P0, P1, 2048, 32, 512,
                                                                 nullptr, nullptr, nullptr, nullptr, nullptr, nullptr);
    addf4_k<<<dim3(4096), dim3(256), 0, stream>>>(P0, P1, out);
}

// Round 14
// 156.783 us; speedup vs baseline: 1.0961x; 1.0961x over previous
//
#include <hip/hip_runtime.h>
#include <hip/hip_bf16.h>

#define SLEN 2048
#define HDIM 2048
#define NHEAD 32
#define KVHEAD 8
#define HEADD 64
#define NTOT 3104
#define NPAD 3200

typedef short bh8 __attribute__((ext_vector_type(8)));
typedef float f32x4 __attribute__((ext_vector_type(4)));

// 0.125 * log2(e): folded into Q so QK^T MFMA emits log2-domain scores
#define QSCALE 0.1803368801111204f

__device__ __forceinline__ unsigned short f2bf(float f) {
    union { float f; unsigned int u; } v; v.f = f;
    unsigned int u = v.u;
    return (unsigned short)((u + 0x7fffu + ((u >> 16) & 1u)) >> 16);
}

// HW packed f32->bf16 (RNE), 1 instruction instead of ~10 bit-ops
__device__ __forceinline__ unsigned int cvtpk_bf16(float lo, float hi) {
    unsigned int r;
    asm("v_cvt_pk_bf16_f32 %0, %1, %2" : "=v"(r) : "v"(lo), "v"(hi));
    return r;
}

__device__ __forceinline__ void gl_lds16(const unsigned short* g, unsigned short* l) {
    __builtin_amdgcn_global_load_lds(
        (const __attribute__((address_space(1))) unsigned int*)g,
        (__attribute__((address_space(3))) unsigned int*)l, 16, 0, 0);
}

// ---------------- RoPE cos/sin table: tab[s*32+d] = (cos, sin) of s*e^(-d*c) ----------------
__global__ void rope_tab_k(float* __restrict__ tab) {
    int i = blockIdx.x * 256 + threadIdx.x;   // 65536 entries
    int s = i >> 5, d = i & 31;
    float invf = __expf(-(float)d * (0.03125f * 13.815510557964274f));
    float ang = (float)s * invf;
    tab[(size_t)i * 2] = cosf(ang);
    tab[(size_t)i * 2 + 1] = sinf(ang);
}

// ---------------- cast hidden fp32 -> bf16 ----------------
__global__ void cast_x_k(const float* __restrict__ src, unsigned short* __restrict__ dst, int n) {
    int i = blockIdx.x * blockDim.x + threadIdx.x;
    int base = i * 4;
    if (base < n) {
        float4 f = *(const float4*)(src + base);
        ushort4 o;
        o.x = f2bf(f.x); o.y = f2bf(f.y); o.z = f2bf(f.z); o.w = f2bf(f.w);
        *(ushort4*)(dst + base) = o;
    }
}

// ---------------- pack [Q | K | V | gates] transposed -> bf16 (NPAD x HDIM) ----------------
__global__ void pack_wt_k(const float* __restrict__ Wq, const float* __restrict__ Wk,
                          const float* __restrict__ Wv, unsigned short* __restrict__ Wt) {
    __shared__ float tile[32][33];
    int n0 = blockIdx.x * 32, k0 = blockIdx.y * 32;
    int t = threadIdx.x;
    for (int i = 0; i < 4; i++) {
        int idx = i * 256 + t;
        int kr = idx >> 5, nc = idx & 31;
        int n = n0 + nc, k = k0 + kr;
        float val = 0.f;
        if (n < 2048)       { int h = n >> 6, d = n & 63; val = Wq[(size_t)k * 2080 + (h >> 2) * 260 + (h & 3) * 64 + d]; }
        else if (n < 2560)  { val = Wk[(size_t)k * 512 + (n - 2048)]; }
        else if (n < 3072)  { val = Wv[(size_t)k * 512 + (n - 2560)]; }
        else if (n < 3104)  { int h = n - 3072;           val = Wq[(size_t)k * 2080 + (h >> 2) * 260 + 256 + (h & 3)]; }
        tile[kr][nc] = val;
    }
    __syncthreads();
    for (int i = 0; i < 4; i++) {
        int idx = i * 256 + t;
        int nr = idx >> 5, kc = idx & 31;
        Wt[(size_t)(n0 + nr) * HDIM + (k0 + kc)] = f2bf(tile[kc][nr]);
    }
}

// ---------------- transpose-cast Wo -> bf16 (2048 x 2048) ----------------
__global__ void pack_wot_k(const float* __restrict__ Wo, unsigned short* __restrict__ Wt) {
    __shared__ float tile[32][33];
    int n0 = blockIdx.x * 32, k0 = blockIdx.y * 32;
    int t = threadIdx.x;
    for (int i = 0; i < 4; i++) {
        int idx = i * 256 + t;
        int kr = idx >> 5, nc = idx & 31;
        tile[kr][nc] = Wo[(size_t)(k0 + kr) * 2048 + (n0 + nc)];
    }
    __syncthreads();
    for (int i = 0; i < 4; i++) {
        int idx = i * 256 + t;
        int nr = idx >> 5, kc = idx & 31;
        Wt[(size_t)(n0 + nr) * 2048 + (k0 + kc)] = f2bf(tile[kc][nr]);
    }
}

// ---------------- NT GEMM, 64x128 tile, templated (R12 structure, unchanged) ----------------
template<int NST, bool FUSE>
__global__ __launch_bounds__(256) void gemm_nt64_k(const unsigned short* __restrict__ A,
                                                   const unsigned short* __restrict__ Bt,
                                                   float* __restrict__ C0,
                                                   float* __restrict__ C1,
                                                   int ldc, int mtiles, int ntiles,
                                                   unsigned short* __restrict__ Qr,
                                                   unsigned short* __restrict__ Kr,
                                                   float* __restrict__ gate,
                                                   const float* __restrict__ g_q,
                                                   const float* __restrict__ g_k,
                                                   const float* __restrict__ tab) {
    const int K = 2048;
    __shared__ unsigned short As[3][64 * 32];
    __shared__ unsigned short Bs[3][128 * 32];
    int d = blockIdx.x;
    int nwg = gridDim.x;
    int cpx = nwg >> 3;
    int swz = (d & 7) * cpx + (d >> 3);
    int half = (swz >= ntiles) ? 1 : 0;
    int tile = swz - half * ntiles;
    int m0 = (tile % mtiles) * 64, n0 = (tile / mtiles) * 128;
    float* C = half ? C1 : C0;
    int koff = half * (NST * 32);
    int t = threadIdx.x;
    int w = t >> 6, l = t & 63;
    int wm = (w >> 1) * 32, wn = (w & 1) * 64;
    int lrow = l & 15, lc = l >> 4;
    int rsw = (lrow >> 1) & 3;
    int scol = ((l & 3) ^ ((l >> 3) & 3)) * 8;

    f32x4 acc[2][4];
    #pragma unroll
    for (int i = 0; i < 2; i++)
        #pragma unroll
        for (int j = 0; j < 4; j++)
            acc[i][j] = {0.f, 0.f, 0.f, 0.f};

    const unsigned short* ga = &A[(size_t)(m0 + w * 16 + (l >> 2)) * K + koff + scol];
    const unsigned short* gb = &Bt[(size_t)(n0 + w * 32 + (l >> 2)) * K + koff + scol];

#define STAGE_NT64(s, b) do { \
        gl_lds16(ga + (size_t)(s) * 32,                  &As[b][w * 512]); \
        gl_lds16(gb + (size_t)(s) * 32,                  &Bs[b][(w * 2 + 0) * 512]); \
        gl_lds16(gb + (size_t)(s) * 32 + 16 * (size_t)K, &Bs[b][(w * 2 + 1) * 512]); \
    } while (0)

#define GBODY(rb) do { \
        bh8 af[2], bb[4]; \
        _Pragma("unroll") \
        for (int i = 0; i < 2; i++) \
            af[i] = *(const bh8*)(&As[rb][(wm + i * 16 + lrow) * 32 + ((lc ^ rsw) * 8)]); \
        _Pragma("unroll") \
        for (int j = 0; j < 4; j++) \
            bb[j] = *(const bh8*)(&Bs[rb][(wn + j * 16 + lrow) * 32 + ((lc ^ rsw) * 8)]); \
        _Pragma("unroll") \
        for (int i = 0; i < 2; i++) \
            _Pragma("unroll") \
            for (int j = 0; j < 4; j++) \
                acc[i][j] = __builtin_amdgcn_mfma_f32_16x16x32_bf16(af[i], bb[j], acc[i][j], 0, 0, 0); \
    } while (0)

#define WB3 asm volatile("s_waitcnt vmcnt(3)\n\ts_barrier" ::: "memory")

    STAGE_NT64(0, 0);
    STAGE_NT64(1, 1);
    if constexpr (NST == 64) {
        for (int sb = 0; sb < 60; sb += 3) {
            WB3;
            STAGE_NT64(sb + 2, 2);
            GBODY(0);
            WB3;
            STAGE_NT64(sb + 3, 0);
            GBODY(1);
            WB3;
            STAGE_NT64(sb + 4, 1);
            GBODY(2);
        }
        WB3;
        STAGE_NT64(62, 2);
        GBODY(0);
        WB3;
        STAGE_NT64(63, 0);
        GBODY(1);
        WB3;
        GBODY(2);
        asm volatile("s_waitcnt vmcnt(0)\n\ts_barrier" ::: "memory");
        GBODY(0);
    } else {
        for (int sb = 0; sb < 30; sb += 3) {
            WB3;
            STAGE_NT64(sb + 2, 2);
            GBODY(0);
            WB3;
            STAGE_NT64(sb + 3, 0);
            GBODY(1);
            WB3;
            STAGE_NT64(sb + 4, 1);
            GBODY(2);
        }
        WB3;
        GBODY(0);
        asm volatile("s_waitcnt vmcnt(0)\n\ts_barrier" ::: "memory");
        GBODY(1);
    }
#undef WB3
#undef STAGE_NT64
#undef GBODY
    int col = l & 15, rbase = (l >> 4) * 4;
    if constexpr (FUSE) {
        int nt = n0 >> 7;
        if (nt < 20) {
            bool isQ = nt < 16;
            int hd = ((n0 + wn) - (isQ ? 0 : 2048)) >> 6;
            unsigned short* dst = (isQ ? Qr : Kr) + (size_t)hd * SLEN * 64;
            const float* gv = isQ ? g_q : g_k;
            float g0 = gv[col], g1 = gv[col + 16], g2 = gv[col + 32], g3 = gv[col + 48];
            float qs = isQ ? QSCALE : 1.0f;
            #pragma unroll
            for (int i = 0; i < 2; i++)
                #pragma unroll
                for (int r = 0; r < 4; r++) {
                    int s = m0 + wm + i * 16 + rbase + r;
                    float x0 = acc[i][0][r], x1 = acc[i][1][r];
                    float x2 = acc[i][2][r], x3 = acc[i][3][r];
                    float sq = x0 * x0 + x1 * x1 + x2 * x2 + x3 * x3;
                    sq += __shfl_xor(sq, 1);
                    sq += __shfl_xor(sq, 2);
                    sq += __shfl_xor(sq, 4);
                    sq += __shfl_xor(sq, 8);
                    float inv = rsqrtf(sq * (1.f / 64.f) + 1e-6f);
                    float xn0 = x0 * inv * g0, xn1 = x1 * inv * g1;
                    float xn2 = x2 * inv * g2, xn3 = x3 * inv * g3;
                    const float* te = tab + (size_t)s * 64;
                    float2 cs0 = *(const float2*)(te + col * 2);
                    float2 cs1 = *(const float2*)(te + (col + 16) * 2);
                    unsigned short* dr = dst + (size_t)s * 64;
                    dr[col]      = f2bf((xn0 * cs0.x - xn2 * cs0.y) * qs);
                    dr[col + 16] = f2bf((xn1 * cs1.x - xn3 * cs1.y) * qs);
                    dr[col + 32] = f2bf((xn2 * cs0.x + xn0 * cs0.y) * qs);
                    dr[col + 48] = f2bf((xn3 * cs1.x + xn1 * cs1.y) * qs);
                }
        } else if (nt < 24) {
            for (int i = 0; i < 2; i++)
                for (int j = 0; j < 4; j++)
                    #pragma unroll
                    for (int r = 0; r < 4; r++)
                        C[(size_t)(m0 + wm + i * 16 + rbase + r) * ldc + (n0 + wn + j * 16 + col)] = acc[i][j][r];
        } else {
            if (wn == 0) {
                #pragma unroll
                for (int i = 0; i < 2; i++)
                    #pragma unroll
                    for (int j = 0; j < 2; j++)
                        #pragma unroll
                        for (int r = 0; r < 4; r++) {
                            int s = m0 + wm + i * 16 + rbase + r;
                            int h = j * 16 + col;
                            gate[s * 32 + h] = 1.f / (1.f + __expf(-acc[i][j][r]));
                        }
            }
        }
    } else {
        for (int i = 0; i < 2; i++)
            for (int j = 0; j < 4; j++)
                #pragma unroll
                for (int r = 0; r < 4; r++)
                    C[(size_t)(m0 + wm + i * 16 + rbase + r) * ldc + (n0 + wn + j * 16 + col)] = acc[i][j][r];
    }
}

// ---------------- out-proj split-K reduce: out = P0 + P1 (2048^2 f32) ----------------
__global__ void addf4_k(const float* __restrict__ a, const float* __restrict__ b,
                        float* __restrict__ o) {
    int i = (blockIdx.x * 256 + threadIdx.x) * 4;
    float4 x = *(const float4*)(a + i);
    float4 y = *(const float4*)(b + i);
    float4 r; r.x = x.x + y.x; r.y = x.y + y.y; r.z = x.z + y.z; r.w = x.w + y.w;
    *(float4*)(o + i) = r;
}

// ---------------- V transpose + key-permute: QKVG[s][2560+hh*64+d] -> Vt[hh][d][perm(s)] ----
__global__ void vt_k(const float* __restrict__ QKVG, unsigned short* __restrict__ Vt) {
    __shared__ float tile[64][65];
    int s0 = blockIdx.x * 64, hh = blockIdx.y;
    int t = threadIdx.x;
    #pragma unroll
    for (int i = 0; i < 4; i++) {
        int idx = i * 256 + t;
        int sr = idx >> 4, c4 = (idx & 15) * 4;
        float4 f = *(const float4*)(&QKVG[(size_t)(s0 + sr) * NPAD + 2560 + hh * 64 + c4]);
        tile[sr][c4] = f.x; tile[sr][c4 + 1] = f.y; tile[sr][c4 + 2] = f.z; tile[sr][c4 + 3] = f.w;
    }
    __syncthreads();
    #pragma unroll
    for (int i = 0; i < 4; i++) {
        int idx = i * 256 + t;
        int dr = idx >> 4, c4 = (idx & 15) * 4;
        int hb = c4 >> 5, f = (c4 >> 4) & 1, g = (c4 >> 2) & 3;
        int p = (hb * 4 + g) * 8 + f * 4;
        ushort4 o;
        o.x = f2bf(tile[c4][dr]); o.y = f2bf(tile[c4 + 1][dr]);
        o.z = f2bf(tile[c4 + 2][dr]); o.w = f2bf(tile[c4 + 3][dr]);
        *(ushort4*)(&Vt[((size_t)hh * 64 + dr) * SLEN + s0 + p]) = o;
    }
}

// ---------------- causal GQA flash attention + gate ----------------
// R14: revert to R12's single-strip structure (1024 blocks; R13's pairing halved the
// grid to 2 blocks/CU and lost -- attn is latency-chain-bound, TLP dominates).
// Occupancy raised via asymmetric buffering: 3 K buffers + 2 V buffers = 40KB LDS
// -> 4 blocks/CU (was 48KB -> 3). Stage order per iter: V(i+1) then K(i+2); needed
// {K(i)@i-2, V(i)@i-1} leave exactly K(i+1)'s 2 loads outstanding -> vmcnt(2).
__global__ __launch_bounds__(256) void attn_k(const unsigned short* __restrict__ Qr,
                                              const unsigned short* __restrict__ Kr,
                                              const unsigned short* __restrict__ Vt,
                                              const float* __restrict__ gate,
                                              unsigned short* __restrict__ attn) {
    __shared__ unsigned short Kls[3][64 * 64];
    __shared__ unsigned short Vls[2][64 * 64];
    int d = blockIdx.x;
    int kvh = d & 7;
    int h = kvh * 4 + ((d >> 3) & 3);
    int qt = 31 - (d >> 5);          // big-first: span-32 blocks dispatch first
    int t = threadIdx.x, w = t >> 6, l = t & 63;
    int ql = l & 15, g = l >> 4;
    const float NEGINF = -__builtin_inff();

    const unsigned short* Kh = Kr + (size_t)kvh * SLEN * 64;
    const unsigned short* Vh = Vt + (size_t)kvh * 64 * SLEN;
    const unsigned short* Qh = Qr + (size_t)h * SLEN * 64;
    int lk = g * 8;
    int r8 = l >> 3, c8 = l & 7;
    int cs = 8 * (c8 ^ r8);          // pre-swizzled source col (shorts)
    int R0 = w * 16, R1 = w * 16 + 8;
    int rdswz = (ql & 7) << 4;       // read-side XOR swizzle (bytes)

    int q0 = qt * 64;
    int qrow = q0 + w * 16 + ql;

    bh8 qa0 = *(const bh8*)(Qh + (size_t)qrow * 64 + lk);
    bh8 qa1 = *(const bh8*)(Qh + (size_t)qrow * 64 + 32 + lk);

    f32x4 o[4];
    #pragma unroll
    for (int i = 0; i < 4; i++) o[i] = {0.f, 0.f, 0.f, 0.f};
    float m2 = NEGINF, lsum = 0.f;

    int ntiles = qt + 1;
    // prologue: V(0)->V[0], K(0)->K[0], K(1)->K[1]  (tile 1 read is always in-bounds:
    // each head has 32 tiles; harmless over-fetch when ntiles==1)
    gl_lds16(&Vh[(size_t)(R0 + r8) * SLEN + 0 + cs], &Vls[0][R0 * 64]);
    gl_lds16(&Vh[(size_t)(R1 + r8) * SLEN + 0 + cs], &Vls[0][R1 * 64]);
    gl_lds16(&Kh[(size_t)(0 + R0 + r8) * 64 + cs], &Kls[0][R0 * 64]);
    gl_lds16(&Kh[(size_t)(0 + R1 + r8) * 64 + cs], &Kls[0][R1 * 64]);
    gl_lds16(&Kh[(size_t)(64 + R0 + r8) * 64 + cs], &Kls[1][R0 * 64]);
    gl_lds16(&Kh[(size_t)(64 + R1 + r8) * 64 + cs], &Kls[1][R1 * 64]);
    int rd = 0, kw = 2;

    for (int ti = 0; ti < ntiles; ti++) {
        // wait: K(ti) staged @ti-2 and V(ti) staged @ti-1 complete; K(ti+1) stays in flight
        if (ti + 1 < ntiles) asm volatile("s_waitcnt vmcnt(2)\n\ts_barrier" ::: "memory");
        else                 asm volatile("s_waitcnt vmcnt(0)\n\ts_barrier" ::: "memory");
        // stage V(ti+1) into V[(ti+1)&1] (last read @ti-1, barrier-ordered)
        if (ti + 1 < ntiles) {
            int kv1 = (ti + 1) * 64;
            gl_lds16(&Vh[(size_t)(R0 + r8) * SLEN + kv1 + cs], &Vls[(ti + 1) & 1][R0 * 64]);
            gl_lds16(&Vh[(size_t)(R1 + r8) * SLEN + kv1 + cs], &Vls[(ti + 1) & 1][R1 * 64]);
        }
        // stage K(ti+2) into K[(ti+2)%3] (last read @ti-1, barrier-ordered)
        if (ti + 2 < ntiles) {
            int kv2 = (ti + 2) * 64;
            gl_lds16(&Kh[(size_t)(kv2 + R0 + r8) * 64 + cs], &Kls[kw][R0 * 64]);
            gl_lds16(&Kh[(size_t)(kv2 + R1 + r8) * 64 + cs], &Kls[kw][R1 * 64]);
        }
        const unsigned short* Kb = &Kls[rd][0];
        const unsigned short* Vb = &Vls[ti & 1][0];
        int kv0 = ti * 64;
        f32x4 sct[4];
        __builtin_amdgcn_s_setprio(1);
        #pragma unroll
        for (int nt = 0; nt < 4; nt++) {
            int rb = (nt * 16 + ql) * 128;
            bh8 kb0 = *(const bh8*)(&Kb[(rb + ((g * 16) ^ rdswz)) >> 1]);
            bh8 kb1 = *(const bh8*)(&Kb[(rb + ((64 + g * 16) ^ rdswz)) >> 1]);
            f32x4 a = {0.f, 0.f, 0.f, 0.f};
            a = __builtin_amdgcn_mfma_f32_16x16x32_bf16(kb0, qa0, a, 0, 0, 0);
            a = __builtin_amdgcn_mfma_f32_16x16x32_bf16(kb1, qa1, a, 0, 0, 0);
            sct[nt] = a;
        }
        __builtin_amdgcn_s_setprio(0);
        if (ti == qt) {
            #pragma unroll
            for (int nt = 0; nt < 4; nt++)
                #pragma unroll
                for (int j = 0; j < 4; j++) {
                    int key = kv0 + nt * 16 + 4 * g + j;
                    if (key > qrow) sct[nt][j] = NEGINF;
                }
        }
        float mt0 = fmaxf(fmaxf(sct[0][0], sct[0][1]), fmaxf(sct[0][2], sct[0][3]));
        float mt1 = fmaxf(fmaxf(sct[1][0], sct[1][1]), fmaxf(sct[1][2], sct[1][3]));
        float mt2 = fmaxf(fmaxf(sct[2][0], sct[2][1]), fmaxf(sct[2][2], sct[2][3]));
        float mt3 = fmaxf(fmaxf(sct[3][0], sct[3][1]), fmaxf(sct[3][2], sct[3][3]));
        float mt = fmaxf(fmaxf(mt0, mt1), fmaxf(mt2, mt3));
        mt = fmaxf(mt, __shfl_xor(mt, 16));
        mt = fmaxf(mt, __shfl_xor(mt, 32));
        if (!__all(mt - m2 <= 8.f)) {
            float mnew = fmaxf(m2, mt);
            float resc = __builtin_amdgcn_exp2f(m2 - mnew);
            m2 = mnew;
            lsum *= resc;
            float rf[4];
            #pragma unroll
            for (int j = 0; j < 4; j++) rf[j] = __shfl(resc, 4 * g + j);
            #pragma unroll
            for (int nt = 0; nt < 4; nt++) {
                f32x4 oo = o[nt];
                #pragma unroll
                for (int j = 0; j < 4; j++) oo[j] *= rf[j];
                o[nt] = oo;
            }
        }
        float ps = 0.f;
        #pragma unroll
        for (int nt = 0; nt < 4; nt++)
            #pragma unroll
            for (int j = 0; j < 4; j++) {
                float p = __builtin_amdgcn_exp2f(sct[nt][j] - m2);
                sct[nt][j] = p;
                ps += p;
            }
        ps += __shfl_xor(ps, 16);
        ps += __shfl_xor(ps, 32);
        lsum += ps;
        union { unsigned int uu[4]; bh8 v; } pa0, pa1;
        pa0.uu[0] = cvtpk_bf16(sct[0][0], sct[0][1]);
        pa0.uu[1] = cvtpk_bf16(sct[0][2], sct[0][3]);
        pa0.uu[2] = cvtpk_bf16(sct[1][0], sct[1][1]);
        pa0.uu[3] = cvtpk_bf16(sct[1][2], sct[1][3]);
        pa1.uu[0] = cvtpk_bf16(sct[2][0], sct[2][1]);
        pa1.uu[1] = cvtpk_bf16(sct[2][2], sct[2][3]);
        pa1.uu[2] = cvtpk_bf16(sct[3][0], sct[3][1]);
        pa1.uu[3] = cvtpk_bf16(sct[3][2], sct[3][3]);
        __builtin_amdgcn_s_setprio(1);
        #pragma unroll
        for (int nt = 0; nt < 4; nt++) {
            int rb = (nt * 16 + ql) * 128;
            bh8 vb0 = *(const bh8*)(&Vb[(rb + ((g * 16) ^ rdswz)) >> 1]);
            bh8 vb1 = *(const bh8*)(&Vb[(rb + ((64 + g * 16) ^ rdswz)) >> 1]);
            o[nt] = __builtin_amdgcn_mfma_f32_16x16x32_bf16(pa0.v, vb0, o[nt], 0, 0, 0);
            o[nt] = __builtin_amdgcn_mfma_f32_16x16x32_bf16(pa1.v, vb1, o[nt], 0, 0, 0);
        }
        __builtin_amdgcn_s_setprio(0);
        rd = (rd == 2) ? 0 : rd + 1;
        kw = (kw == 2) ? 0 : kw + 1;
    }

    float gf[4];
    #pragma unroll
    for (int j = 0; j < 4; j++) {
        float ls = __shfl(lsum, 4 * g + j);
        int row = q0 + w * 16 + 4 * g + j;
        gf[j] = gate[row * 32 + h] / ls;
    }
    #pragma unroll
    for (int j = 0; j < 4; j++) {
        int row = q0 + w * 16 + 4 * g + j;
        #pragma unroll
        for (int nt = 0; nt < 4; nt++)
            attn[(size_t)row * 2048 + h * 64 + nt * 16 + ql] = f2bf(o[nt][j] * gf[j]);
    }
}

extern "C" void kernel_launch(void* const* d_in, const int* in_sizes, int n_in,
                              void* d_out, int out_size, void* d_ws, size_t ws_size,
                              hipStream_t stream) {
    const float* hidden = (const float*)d_in[0];
    const float* Wq = (const float*)d_in[1];
    const float* Wk = (const float*)d_in[2];
    const float* Wv = (const float*)d_in[3];
    const float* Wo = (const float*)d_in[4];
    const float* gq = (const float*)d_in[5];
    const float* gk = (const float*)d_in[6];
    float* out = (float*)d_out;
    char* ws = (char*)d_ws;

    unsigned short* X     = (unsigned short*)(ws + 0);         //  8388608 B
    unsigned short* Wt    = (unsigned short*)(ws + 8388608);   // 13107200 B
    float*          QKVG  = (float*)(ws + 21495808);           // 26214400 B (V cols only; reused as P0)
    unsigned short* Qr    = (unsigned short*)(ws + 47710208);  //  8388608 B
    unsigned short* Kr    = (unsigned short*)(ws + 56098816);  //  2097152 B
    unsigned short* Vt    = (unsigned short*)(ws + 58195968);  //  2097152 B
    float*          gate  = (float*)(ws + 60293120);           //   262144 B
    unsigned short* attnb = (unsigned short*)(ws + 60555264);  //  8388608 B
    unsigned short* Wot   = (unsigned short*)(ws + 68943872);  //  8388608 B
    float*          P1    = (float*)(ws + 77332480);           // 16777216 B (out-proj split-K partial)
    float*          rtab  = (float*)(ws + 94109696);           //   524288 B (RoPE cos/sin table)
    float*          P0    = QKVG;                              // dead after vt_k

    rope_tab_k<<<dim3(256), dim3(256), 0, stream>>>(rtab);
    cast_x_k<<<dim3(4096), dim3(256), 0, stream>>>(hidden, X, SLEN * HDIM);
    pack_wt_k<<<dim3(100, 64), dim3(256), 0, stream>>>(Wq, Wk, Wv, Wt);
    pack_wot_k<<<dim3(64, 64), dim3(256), 0, stream>>>(Wo, Wot);
    gemm_nt64_k<64, true><<<dim3(800), dim3(256), 0, stream>>>(X, Wt, QKVG, QKVG, NPAD, 32, 800,
                                                               Qr, Kr, gate, gq, gk, rtab);
    vt_k<<<dim3(32, 8), dim3(256), 0, stream>>>(QKVG, Vt);
    attn_k<<<dim3(1024), dim3(256), 0, stream>>>(Qr, Kr, Vt, gate, attnb);
    gemm_nt64_k<32, false><<<dim3(1024), dim3(256), 0, stream>>>(attnb, Wot, P0, P1, 2048, 32, 512,
                                                                 nullptr, nullptr, nullptr, nullptr, nullptr, nullptr);
    addf4_k<<<dim3(4096), dim3(256), 0, stream>>>(P0, P1, out);
}

// Round 15
// 153.679 us; speedup vs baseline: 1.1182x; 1.0202x over previous
//
#include <hip/hip_runtime.h>
#include <hip/hip_bf16.h>

#define SLEN 2048
#define HDIM 2048
#define NHEAD 32
#define KVHEAD 8
#define HEADD 64
#define NTOT 3104
#define NPAD 3200

typedef short bh8 __attribute__((ext_vector_type(8)));
typedef float f32x4 __attribute__((ext_vector_type(4)));

// 0.125 * log2(e): folded into Q so QK^T MFMA emits log2-domain scores
#define QSCALE 0.1803368801111204f

__device__ __forceinline__ unsigned short f2bf(float f) {
    union { float f; unsigned int u; } v; v.f = f;
    unsigned int u = v.u;
    return (unsigned short)((u + 0x7fffu + ((u >> 16) & 1u)) >> 16);
}

// HW packed f32->bf16 (RNE), 1 instruction instead of ~10 bit-ops
__device__ __forceinline__ unsigned int cvtpk_bf16(float lo, float hi) {
    unsigned int r;
    asm("v_cvt_pk_bf16_f32 %0, %1, %2" : "=v"(r) : "v"(lo), "v"(hi));
    return r;
}

__device__ __forceinline__ void gl_lds16(const unsigned short* g, unsigned short* l) {
    __builtin_amdgcn_global_load_lds(
        (const __attribute__((address_space(1))) unsigned int*)g,
        (__attribute__((address_space(3))) unsigned int*)l, 16, 0, 0);
}

// ---------------- RoPE cos/sin table: tab[s*32+d] = (cos, sin) of s*e^(-d*c) ----------------
__global__ void rope_tab_k(float* __restrict__ tab) {
    int i = blockIdx.x * 256 + threadIdx.x;   // 65536 entries
    int s = i >> 5, d = i & 31;
    float invf = __expf(-(float)d * (0.03125f * 13.815510557964274f));
    float ang = (float)s * invf;
    tab[(size_t)i * 2] = cosf(ang);
    tab[(size_t)i * 2 + 1] = sinf(ang);
}

// ---------------- cast hidden fp32 -> bf16 ----------------
__global__ void cast_x_k(const float* __restrict__ src, unsigned short* __restrict__ dst, int n) {
    int i = blockIdx.x * blockDim.x + threadIdx.x;
    int base = i * 4;
    if (base < n) {
        float4 f = *(const float4*)(src + base);
        ushort4 o;
        o.x = f2bf(f.x); o.y = f2bf(f.y); o.z = f2bf(f.z); o.w = f2bf(f.w);
        *(ushort4*)(dst + base) = o;
    }
}

// ---------------- pack [Q | K | V | gates] transposed -> bf16 (NPAD x HDIM) ----------------
__global__ void pack_wt_k(const float* __restrict__ Wq, const float* __restrict__ Wk,
                          const float* __restrict__ Wv, unsigned short* __restrict__ Wt) {
    __shared__ float tile[32][33];
    int n0 = blockIdx.x * 32, k0 = blockIdx.y * 32;
    int t = threadIdx.x;
    for (int i = 0; i < 4; i++) {
        int idx = i * 256 + t;
        int kr = idx >> 5, nc = idx & 31;
        int n = n0 + nc, k = k0 + kr;
        float val = 0.f;
        if (n < 2048)       { int h = n >> 6, d = n & 63; val = Wq[(size_t)k * 2080 + (h >> 2) * 260 + (h & 3) * 64 + d]; }
        else if (n < 2560)  { val = Wk[(size_t)k * 512 + (n - 2048)]; }
        else if (n < 3072)  { val = Wv[(size_t)k * 512 + (n - 2560)]; }
        else if (n < 3104)  { int h = n - 3072;           val = Wq[(size_t)k * 2080 + (h >> 2) * 260 + 256 + (h & 3)]; }
        tile[kr][nc] = val;
    }
    __syncthreads();
    for (int i = 0; i < 4; i++) {
        int idx = i * 256 + t;
        int nr = idx >> 5, kc = idx & 31;
        Wt[(size_t)(n0 + nr) * HDIM + (k0 + kc)] = f2bf(tile[kc][nr]);
    }
}

// ---------------- transpose-cast Wo -> bf16 (2048 x 2048) ----------------
__global__ void pack_wot_k(const float* __restrict__ Wo, unsigned short* __restrict__ Wt) {
    __shared__ float tile[32][33];
    int n0 = blockIdx.x * 32, k0 = blockIdx.y * 32;
    int t = threadIdx.x;
    for (int i = 0; i < 4; i++) {
        int idx = i * 256 + t;
        int kr = idx >> 5, nc = idx & 31;
        tile[kr][nc] = Wo[(size_t)(k0 + kr) * 2048 + (n0 + nc)];
    }
    __syncthreads();
    for (int i = 0; i < 4; i++) {
        int idx = i * 256 + t;
        int nr = idx >> 5, kc = idx & 31;
        Wt[(size_t)(n0 + nr) * 2048 + (k0 + kc)] = f2bf(tile[kc][nr]);
    }
}

// ---------------- NT GEMM, 64x128 tile, templated (R12 structure, unchanged) ----------------
template<int NST, bool FUSE>
__global__ __launch_bounds__(256) void gemm_nt64_k(const unsigned short* __restrict__ A,
                                                   const unsigned short* __restrict__ Bt,
                                                   float* __restrict__ C0,
                                                   float* __restrict__ C1,
                                                   int ldc, int mtiles, int ntiles,
                                                   unsigned short* __restrict__ Qr,
                                                   unsigned short* __restrict__ Kr,
                                                   float* __restrict__ gate,
                                                   const float* __restrict__ g_q,
                                                   const float* __restrict__ g_k,
                                                   const float* __restrict__ tab) {
    const int K = 2048;
    __shared__ unsigned short As[3][64 * 32];
    __shared__ unsigned short Bs[3][128 * 32];
    int d = blockIdx.x;
    int nwg = gridDim.x;
    int cpx = nwg >> 3;
    int swz = (d & 7) * cpx + (d >> 3);
    int half = (swz >= ntiles) ? 1 : 0;
    int tile = swz - half * ntiles;
    int m0 = (tile % mtiles) * 64, n0 = (tile / mtiles) * 128;
    float* C = half ? C1 : C0;
    int koff = half * (NST * 32);
    int t = threadIdx.x;
    int w = t >> 6, l = t & 63;
    int wm = (w >> 1) * 32, wn = (w & 1) * 64;
    int lrow = l & 15, lc = l >> 4;
    int rsw = (lrow >> 1) & 3;
    int scol = ((l & 3) ^ ((l >> 3) & 3)) * 8;

    f32x4 acc[2][4];
    #pragma unroll
    for (int i = 0; i < 2; i++)
        #pragma unroll
        for (int j = 0; j < 4; j++)
            acc[i][j] = {0.f, 0.f, 0.f, 0.f};

    const unsigned short* ga = &A[(size_t)(m0 + w * 16 + (l >> 2)) * K + koff + scol];
    const unsigned short* gb = &Bt[(size_t)(n0 + w * 32 + (l >> 2)) * K + koff + scol];

#define STAGE_NT64(s, b) do { \
        gl_lds16(ga + (size_t)(s) * 32,                  &As[b][w * 512]); \
        gl_lds16(gb + (size_t)(s) * 32,                  &Bs[b][(w * 2 + 0) * 512]); \
        gl_lds16(gb + (size_t)(s) * 32 + 16 * (size_t)K, &Bs[b][(w * 2 + 1) * 512]); \
    } while (0)

#define GBODY(rb) do { \
        bh8 af[2], bb[4]; \
        _Pragma("unroll") \
        for (int i = 0; i < 2; i++) \
            af[i] = *(const bh8*)(&As[rb][(wm + i * 16 + lrow) * 32 + ((lc ^ rsw) * 8)]); \
        _Pragma("unroll") \
        for (int j = 0; j < 4; j++) \
            bb[j] = *(const bh8*)(&Bs[rb][(wn + j * 16 + lrow) * 32 + ((lc ^ rsw) * 8)]); \
        _Pragma("unroll") \
        for (int i = 0; i < 2; i++) \
            _Pragma("unroll") \
            for (int j = 0; j < 4; j++) \
                acc[i][j] = __builtin_amdgcn_mfma_f32_16x16x32_bf16(af[i], bb[j], acc[i][j], 0, 0, 0); \
    } while (0)

#define WB3 asm volatile("s_waitcnt vmcnt(3)\n\ts_barrier" ::: "memory")

    STAGE_NT64(0, 0);
    STAGE_NT64(1, 1);
    if constexpr (NST == 64) {
        for (int sb = 0; sb < 60; sb += 3) {
            WB3;
            STAGE_NT64(sb + 2, 2);
            GBODY(0);
            WB3;
            STAGE_NT64(sb + 3, 0);
            GBODY(1);
            WB3;
            STAGE_NT64(sb + 4, 1);
            GBODY(2);
        }
        WB3;
        STAGE_NT64(62, 2);
        GBODY(0);
        WB3;
        STAGE_NT64(63, 0);
        GBODY(1);
        WB3;
        GBODY(2);
        asm volatile("s_waitcnt vmcnt(0)\n\ts_barrier" ::: "memory");
        GBODY(0);
    } else {
        for (int sb = 0; sb < 30; sb += 3) {
            WB3;
            STAGE_NT64(sb + 2, 2);
            GBODY(0);
            WB3;
            STAGE_NT64(sb + 3, 0);
            GBODY(1);
            WB3;
            STAGE_NT64(sb + 4, 1);
            GBODY(2);
        }
        WB3;
        GBODY(0);
        asm volatile("s_waitcnt vmcnt(0)\n\ts_barrier" ::: "memory");
        GBODY(1);
    }
#undef WB3
#undef STAGE_NT64
#undef GBODY
    int col = l & 15, rbase = (l >> 4) * 4;
    if constexpr (FUSE) {
        int nt = n0 >> 7;
        if (nt < 20) {
            bool isQ = nt < 16;
            int hd = ((n0 + wn) - (isQ ? 0 : 2048)) >> 6;
            unsigned short* dst = (isQ ? Qr : Kr) + (size_t)hd * SLEN * 64;
            const float* gv = isQ ? g_q : g_k;
            float g0 = gv[col], g1 = gv[col + 16], g2 = gv[col + 32], g3 = gv[col + 48];
            float qs = isQ ? QSCALE : 1.0f;
            #pragma unroll
            for (int i = 0; i < 2; i++)
                #pragma unroll
                for (int r = 0; r < 4; r++) {
                    int s = m0 + wm + i * 16 + rbase + r;
                    float x0 = acc[i][0][r], x1 = acc[i][1][r];
                    float x2 = acc[i][2][r], x3 = acc[i][3][r];
                    float sq = x0 * x0 + x1 * x1 + x2 * x2 + x3 * x3;
                    sq += __shfl_xor(sq, 1);
                    sq += __shfl_xor(sq, 2);
                    sq += __shfl_xor(sq, 4);
                    sq += __shfl_xor(sq, 8);
                    float inv = rsqrtf(sq * (1.f / 64.f) + 1e-6f);
                    float xn0 = x0 * inv * g0, xn1 = x1 * inv * g1;
                    float xn2 = x2 * inv * g2, xn3 = x3 * inv * g3;
                    const float* te = tab + (size_t)s * 64;
                    float2 cs0 = *(const float2*)(te + col * 2);
                    float2 cs1 = *(const float2*)(te + (col + 16) * 2);
                    unsigned short* dr = dst + (size_t)s * 64;
                    dr[col]      = f2bf((xn0 * cs0.x - xn2 * cs0.y) * qs);
                    dr[col + 16] = f2bf((xn1 * cs1.x - xn3 * cs1.y) * qs);
                    dr[col + 32] = f2bf((xn2 * cs0.x + xn0 * cs0.y) * qs);
                    dr[col + 48] = f2bf((xn3 * cs1.x + xn1 * cs1.y) * qs);
                }
        } else if (nt < 24) {
            for (int i = 0; i < 2; i++)
                for (int j = 0; j < 4; j++)
                    #pragma unroll
                    for (int r = 0; r < 4; r++)
                        C[(size_t)(m0 + wm + i * 16 + rbase + r) * ldc + (n0 + wn + j * 16 + col)] = acc[i][j][r];
        } else {
            if (wn == 0) {
                #pragma unroll
                for (int i = 0; i < 2; i++)
                    #pragma unroll
                    for (int j = 0; j < 2; j++)
                        #pragma unroll
                        for (int r = 0; r < 4; r++) {
                            int s = m0 + wm + i * 16 + rbase + r;
                            int h = j * 16 + col;
                            gate[s * 32 + h] = 1.f / (1.f + __expf(-acc[i][j][r]));
                        }
            }
        }
    } else {
        for (int i = 0; i < 2; i++)
            for (int j = 0; j < 4; j++)
                #pragma unroll
                for (int r = 0; r < 4; r++)
                    C[(size_t)(m0 + wm + i * 16 + rbase + r) * ldc + (n0 + wn + j * 16 + col)] = acc[i][j][r];
    }
}

// ---------------- out-proj split-K reduce: out = P0 + P1 (2048^2 f32) ----------------
__global__ void addf4_k(const float* __restrict__ a, const float* __restrict__ b,
                        float* __restrict__ o) {
    int i = (blockIdx.x * 256 + threadIdx.x) * 4;
    float4 x = *(const float4*)(a + i);
    float4 y = *(const float4*)(b + i);
    float4 r; r.x = x.x + y.x; r.y = x.y + y.y; r.z = x.z + y.z; r.w = x.w + y.w;
    *(float4*)(o + i) = r;
}

// ---------------- V transpose + key-permute: QKVG[s][2560+hh*64+d] -> Vt[hh][d][perm(s)] ----
__global__ void vt_k(const float* __restrict__ QKVG, unsigned short* __restrict__ Vt) {
    __shared__ float tile[64][65];
    int s0 = blockIdx.x * 64, hh = blockIdx.y;
    int t = threadIdx.x;
    #pragma unroll
    for (int i = 0; i < 4; i++) {
        int idx = i * 256 + t;
        int sr = idx >> 4, c4 = (idx & 15) * 4;
        float4 f = *(const float4*)(&QKVG[(size_t)(s0 + sr) * NPAD + 2560 + hh * 64 + c4]);
        tile[sr][c4] = f.x; tile[sr][c4 + 1] = f.y; tile[sr][c4 + 2] = f.z; tile[sr][c4 + 3] = f.w;
    }
    __syncthreads();
    #pragma unroll
    for (int i = 0; i < 4; i++) {
        int idx = i * 256 + t;
        int dr = idx >> 4, c4 = (idx & 15) * 4;
        int hb = c4 >> 5, f = (c4 >> 4) & 1, g = (c4 >> 2) & 3;
        int p = (hb * 4 + g) * 8 + f * 4;
        ushort4 o;
        o.x = f2bf(tile[c4][dr]); o.y = f2bf(tile[c4 + 1][dr]);
        o.z = f2bf(tile[c4 + 2][dr]); o.w = f2bf(tile[c4 + 3][dr]);
        *(ushort4*)(&Vt[((size_t)hh * 64 + dr) * SLEN + s0 + p]) = o;
    }
}

// ---------------- causal GQA flash attention + gate ----------------
// R14 structure (1024 blocks, 3K+2V bufs = 40KB -> 4 blocks/CU, vmcnt(2) pipeline).
// R15: cut 4 cross-lane shfls from the per-tile serial chain:
//  - max check uses LANE-LOCAL mt: __all(local_mt - m2 <= 8) is equivalent to the
//    group-reduced check (m2 is group-uniform, only updated from reduced max); the
//    shfl reduce moves INSIDE the rare rescale branch.
//  - lsum kept lane-local (resc is group-uniform so scaling commutes); cross-lane
//    sum deferred to a single epilogue reduce.
__global__ __launch_bounds__(256) void attn_k(const unsigned short* __restrict__ Qr,
                                              const unsigned short* __restrict__ Kr,
                                              const unsigned short* __restrict__ Vt,
                                              const float* __restrict__ gate,
                                              unsigned short* __restrict__ attn) {
    __shared__ unsigned short Kls[3][64 * 64];
    __shared__ unsigned short Vls[2][64 * 64];
    int d = blockIdx.x;
    int kvh = d & 7;
    int h = kvh * 4 + ((d >> 3) & 3);
    int qt = 31 - (d >> 5);          // big-first: span-32 blocks dispatch first
    int t = threadIdx.x, w = t >> 6, l = t & 63;
    int ql = l & 15, g = l >> 4;
    const float NEGINF = -__builtin_inff();

    const unsigned short* Kh = Kr + (size_t)kvh * SLEN * 64;
    const unsigned short* Vh = Vt + (size_t)kvh * 64 * SLEN;
    const unsigned short* Qh = Qr + (size_t)h * SLEN * 64;
    int lk = g * 8;
    int r8 = l >> 3, c8 = l & 7;
    int cs = 8 * (c8 ^ r8);          // pre-swizzled source col (shorts)
    int R0 = w * 16, R1 = w * 16 + 8;
    int rdswz = (ql & 7) << 4;       // read-side XOR swizzle (bytes)

    int q0 = qt * 64;
    int qrow = q0 + w * 16 + ql;

    bh8 qa0 = *(const bh8*)(Qh + (size_t)qrow * 64 + lk);
    bh8 qa1 = *(const bh8*)(Qh + (size_t)qrow * 64 + 32 + lk);

    f32x4 o[4];
    #pragma unroll
    for (int i = 0; i < 4; i++) o[i] = {0.f, 0.f, 0.f, 0.f};
    float m2 = NEGINF, lsum = 0.f;   // lsum is LANE-LOCAL (reduced once in epilogue)

    int ntiles = qt + 1;
    // prologue: V(0)->V[0], K(0)->K[0], K(1)->K[1]
    gl_lds16(&Vh[(size_t)(R0 + r8) * SLEN + 0 + cs], &Vls[0][R0 * 64]);
    gl_lds16(&Vh[(size_t)(R1 + r8) * SLEN + 0 + cs], &Vls[0][R1 * 64]);
    gl_lds16(&Kh[(size_t)(0 + R0 + r8) * 64 + cs], &Kls[0][R0 * 64]);
    gl_lds16(&Kh[(size_t)(0 + R1 + r8) * 64 + cs], &Kls[0][R1 * 64]);
    gl_lds16(&Kh[(size_t)(64 + R0 + r8) * 64 + cs], &Kls[1][R0 * 64]);
    gl_lds16(&Kh[(size_t)(64 + R1 + r8) * 64 + cs], &Kls[1][R1 * 64]);
    int rd = 0, kw = 2;

    for (int ti = 0; ti < ntiles; ti++) {
        if (ti + 1 < ntiles) asm volatile("s_waitcnt vmcnt(2)\n\ts_barrier" ::: "memory");
        else                 asm volatile("s_waitcnt vmcnt(0)\n\ts_barrier" ::: "memory");
        if (ti + 1 < ntiles) {
            int kv1 = (ti + 1) * 64;
            gl_lds16(&Vh[(size_t)(R0 + r8) * SLEN + kv1 + cs], &Vls[(ti + 1) & 1][R0 * 64]);
            gl_lds16(&Vh[(size_t)(R1 + r8) * SLEN + kv1 + cs], &Vls[(ti + 1) & 1][R1 * 64]);
        }
        if (ti + 2 < ntiles) {
            int kv2 = (ti + 2) * 64;
            gl_lds16(&Kh[(size_t)(kv2 + R0 + r8) * 64 + cs], &Kls[kw][R0 * 64]);
            gl_lds16(&Kh[(size_t)(kv2 + R1 + r8) * 64 + cs], &Kls[kw][R1 * 64]);
        }
        const unsigned short* Kb = &Kls[rd][0];
        const unsigned short* Vb = &Vls[ti & 1][0];
        int kv0 = ti * 64;
        f32x4 sct[4];
        __builtin_amdgcn_s_setprio(1);
        #pragma unroll
        for (int nt = 0; nt < 4; nt++) {
            int rb = (nt * 16 + ql) * 128;
            bh8 kb0 = *(const bh8*)(&Kb[(rb + ((g * 16) ^ rdswz)) >> 1]);
            bh8 kb1 = *(const bh8*)(&Kb[(rb + ((64 + g * 16) ^ rdswz)) >> 1]);
            f32x4 a = {0.f, 0.f, 0.f, 0.f};
            a = __builtin_amdgcn_mfma_f32_16x16x32_bf16(kb0, qa0, a, 0, 0, 0);
            a = __builtin_amdgcn_mfma_f32_16x16x32_bf16(kb1, qa1, a, 0, 0, 0);
            sct[nt] = a;
        }
        __builtin_amdgcn_s_setprio(0);
        if (ti == qt) {
            #pragma unroll
            for (int nt = 0; nt < 4; nt++)
                #pragma unroll
                for (int j = 0; j < 4; j++) {
                    int key = kv0 + nt * 16 + 4 * g + j;
                    if (key > qrow) sct[nt][j] = NEGINF;
                }
        }
        // ---- lane-local max; cross-lane reduce ONLY inside the rare rescale branch
        float mt0 = fmaxf(fmaxf(sct[0][0], sct[0][1]), fmaxf(sct[0][2], sct[0][3]));
        float mt1 = fmaxf(fmaxf(sct[1][0], sct[1][1]), fmaxf(sct[1][2], sct[1][3]));
        float mt2 = fmaxf(fmaxf(sct[2][0], sct[2][1]), fmaxf(sct[2][2], sct[2][3]));
        float mt3 = fmaxf(fmaxf(sct[3][0], sct[3][1]), fmaxf(sct[3][2], sct[3][3]));
        float mt = fmaxf(fmaxf(mt0, mt1), fmaxf(mt2, mt3));
        if (!__all(mt - m2 <= 8.f)) {
            float mtr = fmaxf(mt, __shfl_xor(mt, 16));
            mtr = fmaxf(mtr, __shfl_xor(mtr, 32));
            float mnew = fmaxf(m2, mtr);
            float resc = __builtin_amdgcn_exp2f(m2 - mnew);   // group-uniform
            m2 = mnew;
            lsum *= resc;
            float rf[4];
            #pragma unroll
            for (int j = 0; j < 4; j++) rf[j] = __shfl(resc, 4 * g + j);
            #pragma unroll
            for (int nt = 0; nt < 4; nt++) {
                f32x4 oo = o[nt];
                #pragma unroll
                for (int j = 0; j < 4; j++) oo[j] *= rf[j];
                o[nt] = oo;
            }
        }
        float ps = 0.f;
        #pragma unroll
        for (int nt = 0; nt < 4; nt++)
            #pragma unroll
            for (int j = 0; j < 4; j++) {
                float p = __builtin_amdgcn_exp2f(sct[nt][j] - m2);
                sct[nt][j] = p;
                ps += p;
            }
        lsum += ps;                    // lane-local; no per-tile shuffles
        union { unsigned int uu[4]; bh8 v; } pa0, pa1;
        pa0.uu[0] = cvtpk_bf16(sct[0][0], sct[0][1]);
        pa0.uu[1] = cvtpk_bf16(sct[0][2], sct[0][3]);
        pa0.uu[2] = cvtpk_bf16(sct[1][0], sct[1][1]);
        pa0.uu[3] = cvtpk_bf16(sct[1][2], sct[1][3]);
        pa1.uu[0] = cvtpk_bf16(sct[2][0], sct[2][1]);
        pa1.uu[1] = cvtpk_bf16(sct[2][2], sct[2][3]);
        pa1.uu[2] = cvtpk_bf16(sct[3][0], sct[3][1]);
        pa1.uu[3] = cvtpk_bf16(sct[3][2], sct[3][3]);
        __builtin_amdgcn_s_setprio(1);
        #pragma unroll
        for (int nt = 0; nt < 4; nt++) {
            int rb = (nt * 16 + ql) * 128;
            bh8 vb0 = *(const bh8*)(&Vb[(rb + ((g * 16) ^ rdswz)) >> 1]);
            bh8 vb1 = *(const bh8*)(&Vb[(rb + ((64 + g * 16) ^ rdswz)) >> 1]);
            o[nt] = __builtin_amdgcn_mfma_f32_16x16x32_bf16(pa0.v, vb0, o[nt], 0, 0, 0);
            o[nt] = __builtin_amdgcn_mfma_f32_16x16x32_bf16(pa1.v, vb1, o[nt], 0, 0, 0);
        }
        __builtin_amdgcn_s_setprio(0);
        rd = (rd == 2) ? 0 : rd + 1;
        kw = (kw == 2) ? 0 : kw + 1;
    }

    // ---- epilogue: single deferred lsum reduce, then normalize/gate/store
    lsum += __shfl_xor(lsum, 16);
    lsum += __shfl_xor(lsum, 32);
    float gf[4];
    #pragma unroll
    for (int j = 0; j < 4; j++) {
        float ls = __shfl(lsum, 4 * g + j);
        int row = q0 + w * 16 + 4 * g + j;
        gf[j] = gate[row * 32 + h] / ls;
    }
    #pragma unroll
    for (int j = 0; j < 4; j++) {
        int row = q0 + w * 16 + 4 * g + j;
        #pragma unroll
        for (int nt = 0; nt < 4; nt++)
            attn[(size_t)row * 2048 + h * 64 + nt * 16 + ql] = f2bf(o[nt][j] * gf[j]);
    }
}

extern "C" void kernel_launch(void* const* d_in, const int* in_sizes, int n_in,
                              void* d_out, int out_size, void* d_ws, size_t ws_size,
                              hipStream_t stream) {
    const float* hidden = (const float*)d_in[0];
    const float* Wq = (const float*)d_in[1];
    const float* Wk = (const float*)d_in[2];
    const float* Wv = (const float*)d_in[3];
    const float* Wo = (const float*)d_in[4];
    const float* gq = (const float*)d_in[5];
    const float* gk = (const float*)d_in[6];
    float* out = (float*)d_out;
    char* ws = (char*)d_ws;

    unsigned short* X     = (unsigned short*)(ws + 0);         //  8388608 B
    unsigned short* Wt    = (unsigned short*)(ws + 8388608);   // 13107200 B
    float*          QKVG  = (float*)(ws + 21495808);           // 26214400 B (V cols only; reused as P0)
    unsigned short* Qr    = (unsigned short*)(ws + 47710208);  //  8388608 B
    unsigned short* Kr    = (unsigned short*)(ws + 56098816);  //  2097152 B
    unsigned short* Vt    = (unsigned short*)(ws + 58195968);  //  2097152 B
    float*          gate  = (float*)(ws + 60293120);           //   262144 B
    unsigned short* attnb = (unsigned short*)(ws + 60555264);  //  8388608 B
    unsigned short* Wot   = (unsigned short*)(ws + 68943872);  //  8388608 B
    float*          P1    = (float*)(ws + 77332480);           // 16777216 B (out-proj split-K partial)
    float*          rtab  = (float*)(ws + 94109696);           //   524288 B (RoPE cos/sin table)
    float*          P0    = QKVG;                              // dead after vt_k

    rope_tab_k<<<dim3(256), dim3(256), 0, stream>>>(rtab);
    cast_x_k<<<dim3(4096), dim3(256), 0, stream>>>(hidden, X, SLEN * HDIM);
    pack_wt_k<<<dim3(100, 64), dim3(256), 0, stream>>>(Wq, Wk, Wv, Wt);
    pack_wot_k<<<dim3(64, 64), dim3(256), 0, stream>>>(Wo, Wot);
    gemm_nt64_k<64, true><<<dim3(800), dim3(256), 0, stream>>>(X, Wt, QKVG, QKVG, NPAD, 32, 800,
                                                               Qr, Kr, gate, gq, gk, rtab);
    vt_k<<<dim3(32, 8), dim3(256), 0, stream>>>(QKVG, Vt);
    attn_k<<<dim3(1024), dim3(256), 0, stream>>>(Qr, Kr, Vt, gate, attnb);
    gemm_nt64_k<32, false><<<dim3(1024), dim3(256), 0, stream>>>(attnb, Wot, P0, P1, 2048, 32, 512,
                                                                 nullptr, nullptr, nullptr, nullptr, nullptr, nullptr);
    addf4_k<<<dim3(4096), dim3(256), 0, stream>>>(P0, P1, out);
}

// Round 16
// 143.722 us; speedup vs baseline: 1.1957x; 1.0693x over previous
//
#include <hip/hip_runtime.h>
#include <hip/hip_bf16.h>

#define SLEN 2048
#define HDIM 2048
#define NHEAD 32
#define KVHEAD 8
#define HEADD 64
#define NTOT 3104
#define NPAD 3200

typedef short bh8 __attribute__((ext_vector_type(8)));
typedef float f32x4 __attribute__((ext_vector_type(4)));

// 0.125 * log2(e): folded into Q so QK^T MFMA emits log2-domain scores
#define QSCALE 0.1803368801111204f

__device__ __forceinline__ unsigned short f2bf(float f) {
    union { float f; unsigned int u; } v; v.f = f;
    unsigned int u = v.u;
    return (unsigned short)((u + 0x7fffu + ((u >> 16) & 1u)) >> 16);
}

// HW packed f32->bf16 (RNE), 1 instruction instead of ~10 bit-ops
__device__ __forceinline__ unsigned int cvtpk_bf16(float lo, float hi) {
    unsigned int r;
    asm("v_cvt_pk_bf16_f32 %0, %1, %2" : "=v"(r) : "v"(lo), "v"(hi));
    return r;
}

__device__ __forceinline__ void gl_lds16(const unsigned short* g, unsigned short* l) {
    __builtin_amdgcn_global_load_lds(
        (const __attribute__((address_space(1))) unsigned int*)g,
        (__attribute__((address_space(3))) unsigned int*)l, 16, 0, 0);
}

// ---------------- fused prologue: cast_x | pack_wt | pack_wot | rope_tab ----------------
// R16: the four input-prep kernels are mutually independent and memory-bound; running
// them as one dispatch (blockIdx-range branch, bodies verbatim) lets their heads/tails
// overlap and removes 3 dispatch boundaries (~4-8us of serialization).
// blocks [0,4096): cast_x; [4096,10496): pack_wt (100x64); [10496,14592): pack_wot
// (64x64); [14592,14848): rope_tab.
__global__ void prep_k(const float* __restrict__ hidden, unsigned short* __restrict__ X,
                       const float* __restrict__ Wq, const float* __restrict__ Wk,
                       const float* __restrict__ Wv, unsigned short* __restrict__ Wt,
                       const float* __restrict__ Wo, unsigned short* __restrict__ Wot,
                       float* __restrict__ rtab) {
    __shared__ float tile[32][33];
    int b = blockIdx.x;
    int t = threadIdx.x;
    if (b < 4096) {
        // ---- cast hidden fp32 -> bf16 (4096*256*4 == SLEN*HDIM exactly)
        int base = (b * 256 + t) * 4;
        float4 f = *(const float4*)(hidden + base);
        ushort4 o;
        o.x = f2bf(f.x); o.y = f2bf(f.y); o.z = f2bf(f.z); o.w = f2bf(f.w);
        *(ushort4*)(X + base) = o;
    } else if (b < 10496) {
        // ---- pack [Q | K | V | gates] transposed -> bf16 (NPAD x HDIM)
        int b2 = b - 4096;
        int n0 = (b2 % 100) * 32, k0 = (b2 / 100) * 32;
        for (int i = 0; i < 4; i++) {
            int idx = i * 256 + t;
            int kr = idx >> 5, nc = idx & 31;
            int n = n0 + nc, k = k0 + kr;
            float val = 0.f;
            if (n < 2048)       { int h = n >> 6, d = n & 63; val = Wq[(size_t)k * 2080 + (h >> 2) * 260 + (h & 3) * 64 + d]; }
            else if (n < 2560)  { val = Wk[(size_t)k * 512 + (n - 2048)]; }
            else if (n < 3072)  { val = Wv[(size_t)k * 512 + (n - 2560)]; }
            else if (n < 3104)  { int h = n - 3072;           val = Wq[(size_t)k * 2080 + (h >> 2) * 260 + 256 + (h & 3)]; }
            tile[kr][nc] = val;
        }
        __syncthreads();
        for (int i = 0; i < 4; i++) {
            int idx = i * 256 + t;
            int nr = idx >> 5, kc = idx & 31;
            Wt[(size_t)(n0 + nr) * HDIM + (k0 + kc)] = f2bf(tile[kc][nr]);
        }
    } else if (b < 14592) {
        // ---- transpose-cast Wo -> bf16 (2048 x 2048)
        int b3 = b - 10496;
        int n0 = (b3 & 63) * 32, k0 = (b3 >> 6) * 32;
        for (int i = 0; i < 4; i++) {
            int idx = i * 256 + t;
            int kr = idx >> 5, nc = idx & 31;
            tile[kr][nc] = Wo[(size_t)(k0 + kr) * 2048 + (n0 + nc)];
        }
        __syncthreads();
        for (int i = 0; i < 4; i++) {
            int idx = i * 256 + t;
            int nr = idx >> 5, kc = idx & 31;
            Wot[(size_t)(n0 + nr) * 2048 + (k0 + kc)] = f2bf(tile[kc][nr]);
        }
    } else {
        // ---- RoPE cos/sin table: tab[s*32+d] = (cos, sin) of s*e^(-d*c)
        int i = (b - 14592) * 256 + t;
        int s = i >> 5, d = i & 31;
        float invf = __expf(-(float)d * (0.03125f * 13.815510557964274f));
        float ang = (float)s * invf;
        rtab[(size_t)i * 2] = cosf(ang);
        rtab[(size_t)i * 2 + 1] = sinf(ang);
    }
}

// ---------------- NT GEMM, 64x128 tile, templated (R12 structure, unchanged) ----------------
template<int NST, bool FUSE>
__global__ __launch_bounds__(256) void gemm_nt64_k(const unsigned short* __restrict__ A,
                                                   const unsigned short* __restrict__ Bt,
                                                   float* __restrict__ C0,
                                                   float* __restrict__ C1,
                                                   int ldc, int mtiles, int ntiles,
                                                   unsigned short* __restrict__ Qr,
                                                   unsigned short* __restrict__ Kr,
                                                   float* __restrict__ gate,
                                                   const float* __restrict__ g_q,
                                                   const float* __restrict__ g_k,
                                                   const float* __restrict__ tab) {
    const int K = 2048;
    __shared__ unsigned short As[3][64 * 32];
    __shared__ unsigned short Bs[3][128 * 32];
    int d = blockIdx.x;
    int nwg = gridDim.x;
    int cpx = nwg >> 3;
    int swz = (d & 7) * cpx + (d >> 3);
    int half = (swz >= ntiles) ? 1 : 0;
    int tile = swz - half * ntiles;
    int m0 = (tile % mtiles) * 64, n0 = (tile / mtiles) * 128;
    float* C = half ? C1 : C0;
    int koff = half * (NST * 32);
    int t = threadIdx.x;
    int w = t >> 6, l = t & 63;
    int wm = (w >> 1) * 32, wn = (w & 1) * 64;
    int lrow = l & 15, lc = l >> 4;
    int rsw = (lrow >> 1) & 3;
    int scol = ((l & 3) ^ ((l >> 3) & 3)) * 8;

    f32x4 acc[2][4];
    #pragma unroll
    for (int i = 0; i < 2; i++)
        #pragma unroll
        for (int j = 0; j < 4; j++)
            acc[i][j] = {0.f, 0.f, 0.f, 0.f};

    const unsigned short* ga = &A[(size_t)(m0 + w * 16 + (l >> 2)) * K + koff + scol];
    const unsigned short* gb = &Bt[(size_t)(n0 + w * 32 + (l >> 2)) * K + koff + scol];

#define STAGE_NT64(s, b) do { \
        gl_lds16(ga + (size_t)(s) * 32,                  &As[b][w * 512]); \
        gl_lds16(gb + (size_t)(s) * 32,                  &Bs[b][(w * 2 + 0) * 512]); \
        gl_lds16(gb + (size_t)(s) * 32 + 16 * (size_t)K, &Bs[b][(w * 2 + 1) * 512]); \
    } while (0)

#define GBODY(rb) do { \
        bh8 af[2], bb[4]; \
        _Pragma("unroll") \
        for (int i = 0; i < 2; i++) \
            af[i] = *(const bh8*)(&As[rb][(wm + i * 16 + lrow) * 32 + ((lc ^ rsw) * 8)]); \
        _Pragma("unroll") \
        for (int j = 0; j < 4; j++) \
            bb[j] = *(const bh8*)(&Bs[rb][(wn + j * 16 + lrow) * 32 + ((lc ^ rsw) * 8)]); \
        _Pragma("unroll") \
        for (int i = 0; i < 2; i++) \
            _Pragma("unroll") \
            for (int j = 0; j < 4; j++) \
                acc[i][j] = __builtin_amdgcn_mfma_f32_16x16x32_bf16(af[i], bb[j], acc[i][j], 0, 0, 0); \
    } while (0)

#define WB3 asm volatile("s_waitcnt vmcnt(3)\n\ts_barrier" ::: "memory")

    STAGE_NT64(0, 0);
    STAGE_NT64(1, 1);
    if constexpr (NST == 64) {
        for (int sb = 0; sb < 60; sb += 3) {
            WB3;
            STAGE_NT64(sb + 2, 2);
            GBODY(0);
            WB3;
            STAGE_NT64(sb + 3, 0);
            GBODY(1);
            WB3;
            STAGE_NT64(sb + 4, 1);
            GBODY(2);
        }
        WB3;
        STAGE_NT64(62, 2);
        GBODY(0);
        WB3;
        STAGE_NT64(63, 0);
        GBODY(1);
        WB3;
        GBODY(2);
        asm volatile("s_waitcnt vmcnt(0)\n\ts_barrier" ::: "memory");
        GBODY(0);
    } else {
        for (int sb = 0; sb < 30; sb += 3) {
            WB3;
            STAGE_NT64(sb + 2, 2);
            GBODY(0);
            WB3;
            STAGE_NT64(sb + 3, 0);
            GBODY(1);
            WB3;
            STAGE_NT64(sb + 4, 1);
            GBODY(2);
        }
        WB3;
        GBODY(0);
        asm volatile("s_waitcnt vmcnt(0)\n\ts_barrier" ::: "memory");
        GBODY(1);
    }
#undef WB3
#undef STAGE_NT64
#undef GBODY
    int col = l & 15, rbase = (l >> 4) * 4;
    if constexpr (FUSE) {
        int nt = n0 >> 7;
        if (nt < 20) {
            bool isQ = nt < 16;
            int hd = ((n0 + wn) - (isQ ? 0 : 2048)) >> 6;
            unsigned short* dst = (isQ ? Qr : Kr) + (size_t)hd * SLEN * 64;
            const float* gv = isQ ? g_q : g_k;
            float g0 = gv[col], g1 = gv[col + 16], g2 = gv[col + 32], g3 = gv[col + 48];
            float qs = isQ ? QSCALE : 1.0f;
            #pragma unroll
            for (int i = 0; i < 2; i++)
                #pragma unroll
                for (int r = 0; r < 4; r++) {
                    int s = m0 + wm + i * 16 + rbase + r;
                    float x0 = acc[i][0][r], x1 = acc[i][1][r];
                    float x2 = acc[i][2][r], x3 = acc[i][3][r];
                    float sq = x0 * x0 + x1 * x1 + x2 * x2 + x3 * x3;
                    sq += __shfl_xor(sq, 1);
                    sq += __shfl_xor(sq, 2);
                    sq += __shfl_xor(sq, 4);
                    sq += __shfl_xor(sq, 8);
                    float inv = rsqrtf(sq * (1.f / 64.f) + 1e-6f);
                    float xn0 = x0 * inv * g0, xn1 = x1 * inv * g1;
                    float xn2 = x2 * inv * g2, xn3 = x3 * inv * g3;
                    const float* te = tab + (size_t)s * 64;
                    float2 cs0 = *(const float2*)(te + col * 2);
                    float2 cs1 = *(const float2*)(te + (col + 16) * 2);
                    unsigned short* dr = dst + (size_t)s * 64;
                    dr[col]      = f2bf((xn0 * cs0.x - xn2 * cs0.y) * qs);
                    dr[col + 16] = f2bf((xn1 * cs1.x - xn3 * cs1.y) * qs);
                    dr[col + 32] = f2bf((xn2 * cs0.x + xn0 * cs0.y) * qs);
                    dr[col + 48] = f2bf((xn3 * cs1.x + xn1 * cs1.y) * qs);
                }
        } else if (nt < 24) {
            for (int i = 0; i < 2; i++)
                for (int j = 0; j < 4; j++)
                    #pragma unroll
                    for (int r = 0; r < 4; r++)
                        C[(size_t)(m0 + wm + i * 16 + rbase + r) * ldc + (n0 + wn + j * 16 + col)] = acc[i][j][r];
        } else {
            if (wn == 0) {
                #pragma unroll
                for (int i = 0; i < 2; i++)
                    #pragma unroll
                    for (int j = 0; j < 2; j++)
                        #pragma unroll
                        for (int r = 0; r < 4; r++) {
                            int s = m0 + wm + i * 16 + rbase + r;
                            int h = j * 16 + col;
                            gate[s * 32 + h] = 1.f / (1.f + __expf(-acc[i][j][r]));
                        }
            }
        }
    } else {
        for (int i = 0; i < 2; i++)
            for (int j = 0; j < 4; j++)
                #pragma unroll
                for (int r = 0; r < 4; r++)
                    C[(size_t)(m0 + wm + i * 16 + rbase + r) * ldc + (n0 + wn + j * 16 + col)] = acc[i][j][r];
    }
}

// ---------------- out-proj split-K reduce: out = P0 + P1 (2048^2 f32) ----------------
__global__ void addf4_k(const float* __restrict__ a, const float* __restrict__ b,
                        float* __restrict__ o) {
    int i = (blockIdx.x * 256 + threadIdx.x) * 4;
    float4 x = *(const float4*)(a + i);
    float4 y = *(const float4*)(b + i);
    float4 r; r.x = x.x + y.x; r.y = x.y + y.y; r.z = x.z + y.z; r.w = x.w + y.w;
    *(float4*)(o + i) = r;
}

// ---------------- V transpose + key-permute: QKVG[s][2560+hh*64+d] -> Vt[hh][d][perm(s)] ----
__global__ void vt_k(const float* __restrict__ QKVG, unsigned short* __restrict__ Vt) {
    __shared__ float tile[64][65];
    int s0 = blockIdx.x * 64, hh = blockIdx.y;
    int t = threadIdx.x;
    #pragma unroll
    for (int i = 0; i < 4; i++) {
        int idx = i * 256 + t;
        int sr = idx >> 4, c4 = (idx & 15) * 4;
        float4 f = *(const float4*)(&QKVG[(size_t)(s0 + sr) * NPAD + 2560 + hh * 64 + c4]);
        tile[sr][c4] = f.x; tile[sr][c4 + 1] = f.y; tile[sr][c4 + 2] = f.z; tile[sr][c4 + 3] = f.w;
    }
    __syncthreads();
    #pragma unroll
    for (int i = 0; i < 4; i++) {
        int idx = i * 256 + t;
        int dr = idx >> 4, c4 = (idx & 15) * 4;
        int hb = c4 >> 5, f = (c4 >> 4) & 1, g = (c4 >> 2) & 3;
        int p = (hb * 4 + g) * 8 + f * 4;
        ushort4 o;
        o.x = f2bf(tile[c4][dr]); o.y = f2bf(tile[c4 + 1][dr]);
        o.z = f2bf(tile[c4 + 2][dr]); o.w = f2bf(tile[c4 + 3][dr]);
        *(ushort4*)(&Vt[((size_t)hh * 64 + dr) * SLEN + s0 + p]) = o;
    }
}

// ---------------- causal GQA flash attention + gate (R15 structure, unchanged) ----------------
__global__ __launch_bounds__(256) void attn_k(const unsigned short* __restrict__ Qr,
                                              const unsigned short* __restrict__ Kr,
                                              const unsigned short* __restrict__ Vt,
                                              const float* __restrict__ gate,
                                              unsigned short* __restrict__ attn) {
    __shared__ unsigned short Kls[3][64 * 64];
    __shared__ unsigned short Vls[2][64 * 64];
    int d = blockIdx.x;
    int kvh = d & 7;
    int h = kvh * 4 + ((d >> 3) & 3);
    int qt = 31 - (d >> 5);          // big-first: span-32 blocks dispatch first
    int t = threadIdx.x, w = t >> 6, l = t & 63;
    int ql = l & 15, g = l >> 4;
    const float NEGINF = -__builtin_inff();

    const unsigned short* Kh = Kr + (size_t)kvh * SLEN * 64;
    const unsigned short* Vh = Vt + (size_t)kvh * 64 * SLEN;
    const unsigned short* Qh = Qr + (size_t)h * SLEN * 64;
    int lk = g * 8;
    int r8 = l >> 3, c8 = l & 7;
    int cs = 8 * (c8 ^ r8);          // pre-swizzled source col (shorts)
    int R0 = w * 16, R1 = w * 16 + 8;
    int rdswz = (ql & 7) << 4;       // read-side XOR swizzle (bytes)

    int q0 = qt * 64;
    int qrow = q0 + w * 16 + ql;

    bh8 qa0 = *(const bh8*)(Qh + (size_t)qrow * 64 + lk);
    bh8 qa1 = *(const bh8*)(Qh + (size_t)qrow * 64 + 32 + lk);

    f32x4 o[4];
    #pragma unroll
    for (int i = 0; i < 4; i++) o[i] = {0.f, 0.f, 0.f, 0.f};
    float m2 = NEGINF, lsum = 0.f;   // lsum lane-local (reduced once in epilogue)

    int ntiles = qt + 1;
    gl_lds16(&Vh[(size_t)(R0 + r8) * SLEN + 0 + cs], &Vls[0][R0 * 64]);
    gl_lds16(&Vh[(size_t)(R1 + r8) * SLEN + 0 + cs], &Vls[0][R1 * 64]);
    gl_lds16(&Kh[(size_t)(0 + R0 + r8) * 64 + cs], &Kls[0][R0 * 64]);
    gl_lds16(&Kh[(size_t)(0 + R1 + r8) * 64 + cs], &Kls[0][R1 * 64]);
    gl_lds16(&Kh[(size_t)(64 + R0 + r8) * 64 + cs], &Kls[1][R0 * 64]);
    gl_lds16(&Kh[(size_t)(64 + R1 + r8) * 64 + cs], &Kls[1][R1 * 64]);
    int rd = 0, kw = 2;

    for (int ti = 0; ti < ntiles; ti++) {
        if (ti + 1 < ntiles) asm volatile("s_waitcnt vmcnt(2)\n\ts_barrier" ::: "memory");
        else                 asm volatile("s_waitcnt vmcnt(0)\n\ts_barrier" ::: "memory");
        if (ti + 1 < ntiles) {
            int kv1 = (ti + 1) * 64;
            gl_lds16(&Vh[(size_t)(R0 + r8) * SLEN + kv1 + cs], &Vls[(ti + 1) & 1][R0 * 64]);
            gl_lds16(&Vh[(size_t)(R1 + r8) * SLEN + kv1 + cs], &Vls[(ti + 1) & 1][R1 * 64]);
        }
        if (ti + 2 < ntiles) {
            int kv2 = (ti + 2) * 64;
            gl_lds16(&Kh[(size_t)(kv2 + R0 + r8) * 64 + cs], &Kls[kw][R0 * 64]);
            gl_lds16(&Kh[(size_t)(kv2 + R1 + r8) * 64 + cs], &Kls[kw][R1 * 64]);
        }
        const unsigned short* Kb = &Kls[rd][0];
        const unsigned short* Vb = &Vls[ti & 1][0];
        int kv0 = ti * 64;
        f32x4 sct[4];
        __builtin_amdgcn_s_setprio(1);
        #pragma unroll
        for (int nt = 0; nt < 4; nt++) {
            int rb = (nt * 16 + ql) * 128;
            bh8 kb0 = *(const bh8*)(&Kb[(rb + ((g * 16) ^ rdswz)) >> 1]);
            bh8 kb1 = *(const bh8*)(&Kb[(rb + ((64 + g * 16) ^ rdswz)) >> 1]);
            f32x4 a = {0.f, 0.f, 0.f, 0.f};
            a = __builtin_amdgcn_mfma_f32_16x16x32_bf16(kb0, qa0, a, 0, 0, 0);
            a = __builtin_amdgcn_mfma_f32_16x16x32_bf16(kb1, qa1, a, 0, 0, 0);
            sct[nt] = a;
        }
        __builtin_amdgcn_s_setprio(0);
        if (ti == qt) {
            #pragma unroll
            for (int nt = 0; nt < 4; nt++)
                #pragma unroll
                for (int j = 0; j < 4; j++) {
                    int key = kv0 + nt * 16 + 4 * g + j;
                    if (key > qrow) sct[nt][j] = NEGINF;
                }
        }
        float mt0 = fmaxf(fmaxf(sct[0][0], sct[0][1]), fmaxf(sct[0][2], sct[0][3]));
        float mt1 = fmaxf(fmaxf(sct[1][0], sct[1][1]), fmaxf(sct[1][2], sct[1][3]));
        float mt2 = fmaxf(fmaxf(sct[2][0], sct[2][1]), fmaxf(sct[2][2], sct[2][3]));
        float mt3 = fmaxf(fmaxf(sct[3][0], sct[3][1]), fmaxf(sct[3][2], sct[3][3]));
        float mt = fmaxf(fmaxf(mt0, mt1), fmaxf(mt2, mt3));
        if (!__all(mt - m2 <= 8.f)) {
            float mtr = fmaxf(mt, __shfl_xor(mt, 16));
            mtr = fmaxf(mtr, __shfl_xor(mtr, 32));
            float mnew = fmaxf(m2, mtr);
            float resc = __builtin_amdgcn_exp2f(m2 - mnew);   // group-uniform
            m2 = mnew;
            lsum *= resc;
            float rf[4];
            #pragma unroll
            for (int j = 0; j < 4; j++) rf[j] = __shfl(resc, 4 * g + j);
            #pragma unroll
            for (int nt = 0; nt < 4; nt++) {
                f32x4 oo = o[nt];
                #pragma unroll
                for (int j = 0; j < 4; j++) oo[j] *= rf[j];
                o[nt] = oo;
            }
        }
        float ps = 0.f;
        #pragma unroll
        for (int nt = 0; nt < 4; nt++)
            #pragma unroll
            for (int j = 0; j < 4; j++) {
                float p = __builtin_amdgcn_exp2f(sct[nt][j] - m2);
                sct[nt][j] = p;
                ps += p;
            }
        lsum += ps;                    // lane-local; no per-tile shuffles
        union { unsigned int uu[4]; bh8 v; } pa0, pa1;
        pa0.uu[0] = cvtpk_bf16(sct[0][0], sct[0][1]);
        pa0.uu[1] = cvtpk_bf16(sct[0][2], sct[0][3]);
        pa0.uu[2] = cvtpk_bf16(sct[1][0], sct[1][1]);
        pa0.uu[3] = cvtpk_bf16(sct[1][2], sct[1][3]);
        pa1.uu[0] = cvtpk_bf16(sct[2][0], sct[2][1]);
        pa1.uu[1] = cvtpk_bf16(sct[2][2], sct[2][3]);
        pa1.uu[2] = cvtpk_bf16(sct[3][0], sct[3][1]);
        pa1.uu[3] = cvtpk_bf16(sct[3][2], sct[3][3]);
        __builtin_amdgcn_s_setprio(1);
        #pragma unroll
        for (int nt = 0; nt < 4; nt++) {
            int rb = (nt * 16 + ql) * 128;
            bh8 vb0 = *(const bh8*)(&Vb[(rb + ((g * 16) ^ rdswz)) >> 1]);
            bh8 vb1 = *(const bh8*)(&Vb[(rb + ((64 + g * 16) ^ rdswz)) >> 1]);
            o[nt] = __builtin_amdgcn_mfma_f32_16x16x32_bf16(pa0.v, vb0, o[nt], 0, 0, 0);
            o[nt] = __builtin_amdgcn_mfma_f32_16x16x32_bf16(pa1.v, vb1, o[nt], 0, 0, 0);
        }
        __builtin_amdgcn_s_setprio(0);
        rd = (rd == 2) ? 0 : rd + 1;
        kw = (kw == 2) ? 0 : kw + 1;
    }

    lsum += __shfl_xor(lsum, 16);
    lsum += __shfl_xor(lsum, 32);
    float gf[4];
    #pragma unroll
    for (int j = 0; j < 4; j++) {
        float ls = __shfl(lsum, 4 * g + j);
        int row = q0 + w * 16 + 4 * g + j;
        gf[j] = gate[row * 32 + h] / ls;
    }
    #pragma unroll
    for (int j = 0; j < 4; j++) {
        int row = q0 + w * 16 + 4 * g + j;
        #pragma unroll
        for (int nt = 0; nt < 4; nt++)
            attn[(size_t)row * 2048 + h * 64 + nt * 16 + ql] = f2bf(o[nt][j] * gf[j]);
    }
}

extern "C" void kernel_launch(void* const* d_in, const int* in_sizes, int n_in,
                              void* d_out, int out_size, void* d_ws, size_t ws_size,
                              hipStream_t stream) {
    const float* hidden = (const float*)d_in[0];
    const float* Wq = (const float*)d_in[1];
    const float* Wk = (const float*)d_in[2];
    const float* Wv = (const float*)d_in[3];
    const float* Wo = (const float*)d_in[4];
    const float* gq = (const float*)d_in[5];
    const float* gk = (const float*)d_in[6];
    float* out = (float*)d_out;
    char* ws = (char*)d_ws;

    unsigned short* X     = (unsigned short*)(ws + 0);         //  8388608 B
    unsigned short* Wt    = (unsigned short*)(ws + 8388608);   // 13107200 B
    float*          QKVG  = (float*)(ws + 21495808);           // 26214400 B (V cols only; reused as P0)
    unsigned short* Qr    = (unsigned short*)(ws + 47710208);  //  8388608 B
    unsigned short* Kr    = (unsigned short*)(ws + 56098816);  //  2097152 B
    unsigned short* Vt    = (unsigned short*)(ws + 58195968);  //  2097152 B
    float*          gate  = (float*)(ws + 60293120);           //   262144 B
    unsigned short* attnb = (unsigned short*)(ws + 60555264);  //  8388608 B
    unsigned short* Wot   = (unsigned short*)(ws + 68943872);  //  8388608 B
    float*          P1    = (float*)(ws + 77332480);           // 16777216 B (out-proj split-K partial)
    float*          rtab  = (float*)(ws + 94109696);           //   524288 B (RoPE cos/sin table)
    float*          P0    = QKVG;                              // dead after vt_k

    prep_k<<<dim3(14848), dim3(256), 0, stream>>>(hidden, X, Wq, Wk, Wv, Wt, Wo, Wot, rtab);
    gemm_nt64_k<64, true><<<dim3(800), dim3(256), 0, stream>>>(X, Wt, QKVG, QKVG, NPAD, 32, 800,
                                                               Qr, Kr, gate, gq, gk, rtab);
    vt_k<<<dim3(32, 8), dim3(256), 0, stream>>>(QKVG, Vt);
    attn_k<<<dim3(1024), dim3(256), 0, stream>>>(Qr, Kr, Vt, gate, attnb);
    gemm_nt64_k<32, false><<<dim3(1024), dim3(256), 0, stream>>>(attnb, Wot, P0, P1, 2048, 32, 512,
                                                                 nullptr, nullptr, nullptr, nullptr, nullptr, nullptr);
    addf4_k<<<dim3(4096), dim3(256), 0, stream>>>(P0, P1, out);
}